// Round 15
// baseline (338.072 us; speedup 1.0000x reference)
//
#include <hip/hip_runtime.h>
#include <hip/hip_bf16.h>

#define BB 8
#define TT 4096
#define NHH 16
#define MDD 64
#define FFF 256
#define HEADSS 4
#define DHH 16
#define PEHH 32

#define GM (BB * TT)      // 32768
#define GK 1024
#define GN 1024
#define BMt 128
#define BNt 128
#define BKt 64
#define NCHUNK (GN / BNt) // 8

#define TOKW 4            // tokens per k_main block (1 wave each)

typedef float f32x4 __attribute__((ext_vector_type(4)));
typedef short bf16x8 __attribute__((ext_vector_type(8)));

static __device__ __forceinline__ float lrelu(float x) { return x > 0.0f ? x : 0.2f * x; }
static __device__ __forceinline__ unsigned long long umin64(unsigned long long a, unsigned long long b) {
    return a < b ? a : b;
}
static __device__ __forceinline__ unsigned short f2bf(float f) {
    __bf16 b = (__bf16)f;                       // native RNE cvt; pairs fuse to v_cvt_pk_bf16_f32
    return __builtin_bit_cast(unsigned short, b);
}
static __device__ __forceinline__ float bf2f(unsigned short u) {
    return __uint_as_float(((unsigned)u) << 16);
}
static __device__ __forceinline__ unsigned pk2(float a, float b) {
    return (unsigned)f2bf(a) | ((unsigned)f2bf(b) << 16);
}
static __device__ __forceinline__ void gload16(const void* g, void* l) {
    __builtin_amdgcn_global_load_lds((const __attribute__((address_space(1))) unsigned int*)g,
                                     (__attribute__((address_space(3))) unsigned int*)l, 16, 0, 0);
}

// ---------------- Kernel 1: fused front (NN-search+bias | LN1 | Wall pack | Wu1 transpose) ----
// blocks [0,4096): NN+bias; [4096,12288): LN1; [12288,12416): Wall; [12416,13440): Wu1t.
__global__ __launch_bounds__(256) void k_front(const float* __restrict__ c1,
                                               const float* __restrict__ c2,
                                               const float* __restrict__ Wp1,
                                               const float* __restrict__ bp1,
                                               const float* __restrict__ Wp2,
                                               const float* __restrict__ bp2,
                                               int* __restrict__ idx,
                                               float* __restrict__ c1n,
                                               float* __restrict__ c2n,
                                               float* __restrict__ bias,
                                               const float* __restrict__ x,
                                               const float* __restrict__ g1,
                                               const float* __restrict__ be1,
                                               unsigned short* __restrict__ xn,
                                               const float* __restrict__ Wq, const float* __restrict__ Wk,
                                               const float* __restrict__ Wv, const float* __restrict__ Wo,
                                               const float* __restrict__ Wn1,
                                               unsigned short* __restrict__ Wall,
                                               const float* __restrict__ W,
                                               unsigned short* __restrict__ Wt) {
    int blk = blockIdx.x;
    int tid = threadIdx.x;
    if (blk < TT) {
        // ---- NN search + fused bias MLP ----
        int t = blk;
        int lane = tid & 63, w = tid >> 6;
        __shared__ unsigned long long stage[4 * NHH];
        __shared__ float sc1[NHH], sc2[NHH];
        __shared__ float sWp1[2 * PEHH], sbp1[PEHH], sWp2[PEHH * HEADSS], sbp2[HEADSS];
        if (tid < 2 * PEHH) sWp1[tid] = Wp1[tid];
        if (tid < PEHH) sbp1[tid] = bp1[tid];
        if (tid < PEHH * HEADSS) sWp2[tid] = Wp2[tid];
        if (tid < HEADSS) sbp2[tid] = bp2[tid];
        float c1t = c1[t], c2t = c2[t];

        unsigned long long keys[16];
        #pragma unroll
        for (int i = 0; i < 16; ++i) {
            int j = i * 256 + tid;
            float d1 = __fsub_rn(c1[j], c1t);
            float d2 = __fsub_rn(c2[j], c2t);
            float dist = __fadd_rn(__fmul_rn(d1, d1), __fmul_rn(d2, d2));
            keys[i] = (((unsigned long long)__float_as_uint(dist)) << 32) | (unsigned)j;
        }

        #pragma unroll 1
        for (int s = 0; s < NHH; ++s) {
            unsigned long long m = keys[0];
            #pragma unroll
            for (int i = 1; i < 16; ++i) m = umin64(m, keys[i]);
            #pragma unroll
            for (int off = 1; off < 64; off <<= 1)
                m = umin64(m, (unsigned long long)__shfl_xor((long long)m, off));
            #pragma unroll
            for (int i = 0; i < 16; ++i)
                if (keys[i] == m) keys[i] = ~0ull;
            if (lane == 0) stage[w * NHH + s] = m;
        }
        __syncthreads();

        if (w == 0) {
            unsigned long long k0 = stage[lane];
            #pragma unroll 1
            for (int s = 0; s < NHH; ++s) {
                unsigned long long m = k0;
                #pragma unroll
                for (int off = 1; off < 64; off <<= 1)
                    m = umin64(m, (unsigned long long)__shfl_xor((long long)m, off));
                if (k0 == m) k0 = ~0ull;
                if (lane == 0) {
                    int jj = (int)(unsigned)(m & 0xffffffffu);
                    float v1 = __fsub_rn(c1[jj], c1t);
                    float v2 = __fsub_rn(c2[jj], c2t);
                    idx[t * NHH + s] = jj;
                    c1n[t * NHH + s] = v1;
                    c2n[t * NHH + s] = v2;
                    sc1[s] = v1;
                    sc2[s] = v2;
                }
            }
        }
        __syncthreads();

        {
            int j = tid & 15, i = tid >> 4;
            float p1 = sc1[i] - sc1[j];
            float p2 = sc2[i] - sc2[j];
            float acc0 = sbp2[0], acc1 = sbp2[1], acc2 = sbp2[2], acc3 = sbp2[3];
            #pragma unroll
            for (int kk = 0; kk < PEHH; ++kk) {
                float h = lrelu(p1 * sWp1[kk] + p2 * sWp1[PEHH + kk] + sbp1[kk]);
                acc0 += h * sWp2[kk * HEADSS + 0];
                acc1 += h * sWp2[kk * HEADSS + 1];
                acc2 += h * sWp2[kk * HEADSS + 2];
                acc3 += h * sWp2[kk * HEADSS + 3];
            }
            float* bt = bias + (size_t)t * HEADSS * NHH * NHH;
            bt[0 * 256 + i * NHH + j] = acc0;
            bt[1 * 256 + i * NHH + j] = acc1;
            bt[2 * 256 + i * NHH + j] = acc2;
            bt[3 * 256 + i * NHH + j] = acc3;
        }
        return;
    }
    blk -= TT;
    if (blk < (BB * TT) / 4) {
        int row = blk * 4 + (tid >> 6);
        int lane = tid & 63;
        float v = x[(size_t)row * MDD + lane];
        float s = v;
        for (int off = 32; off > 0; off >>= 1) s += __shfl_down(s, off);
        s = __shfl(s, 0);
        float m = s * (1.0f / 64.0f);
        float d = v - m;
        float sq = d * d;
        for (int off = 32; off > 0; off >>= 1) sq += __shfl_down(sq, off);
        sq = __shfl(sq, 0);
        float var = sq * (1.0f / 64.0f);
        float inv = 1.0f / sqrtf(var + 1e-5f);
        xn[(size_t)row * MDD + lane] = f2bf(d * inv * g1[lane] + be1[lane]);
        return;
    }
    blk -= (BB * TT) / 4;
    if (blk < 128) {
        int id = blk * 256 + tid;
        int f = id >> 9;
        int wv = (id >> 3) & 63;
        int e = id & 7;
        int li = wv & 15, G = wv >> 4;
        float v;
        if (f < 24) {
            int mt = f >> 1, ks = f & 1;
            int n = mt * 16 + li;
            int k = ks * 32 + G * 8 + e;
            v = (n < 64) ? Wq[k * 64 + n] : (n < 128) ? Wk[k * 64 + (n - 64)] : Wv[k * 64 + (n - 128)];
        } else if (f < 32) {
            int g2i = f - 24;
            int mt = g2i >> 1, ks = g2i & 1;
            int n = mt * 16 + li;
            int k = ks * 32 + G * 8 + e;
            v = Wo[k * 64 + n];
        } else {
            int g2i = f - 32;
            int mt = g2i >> 1, ks = g2i & 1;
            int n = mt * 16 + li;
            int k = ks * 32 + G * 8 + e;
            v = Wn1[k * 256 + n];
        }
        Wall[id] = f2bf(v);
        return;
    }
    blk -= 128;
    {
        __shared__ float tile[32][33];
        int tk = blk & 31;
        int tn = blk >> 5;
        int c = tid & 31, r4 = tid >> 5;
        #pragma unroll
        for (int p = 0; p < 4; ++p) {
            int r = p * 8 + r4;
            tile[r][c] = W[(size_t)(tk * 32 + r) * GN + tn * 32 + c];
        }
        __syncthreads();
        #pragma unroll
        for (int p = 0; p < 4; ++p) {
            int r = p * 8 + r4;
            int n = tn * 32 + r;
            int kk = tk * 32 + c;
            int chunk = kk >> 6, slot = (kk >> 3) & 7, e = kk & 7;
            Wt[(size_t)n * GK + chunk * 64 + ((slot ^ (n & 7)) << 3) + e] = f2bf(tile[c][r]);
        }
    }
}

// ---------------- Kernel 4: fused block kernel, weights from L2; LDS-capped occupancy ----------------
__global__ __launch_bounds__(256) void k_main(const unsigned short* __restrict__ xnb,
                                              const int* __restrict__ idx,
                                              const float* __restrict__ bias,
                                              const unsigned short* __restrict__ Wall,
                                              const float* __restrict__ bq, const float* __restrict__ bk,
                                              const float* __restrict__ bv, const float* __restrict__ ls,
                                              const float* __restrict__ bo,
                                              const float* __restrict__ g2, const float* __restrict__ be2,
                                              const float* __restrict__ bn1, const float* __restrict__ Wn2,
                                              const float* __restrict__ bn2,
                                              const float* __restrict__ g3, const float* __restrict__ be3,
                                              unsigned short* __restrict__ xu) {
    __shared__ __align__(16) char L[TOKW * 8192];   // 32 KB -> LDS allows 5 blocks/CU
    const int tid = threadIdx.x;
    const int lane = tid & 63;
    const int li = lane & 15;
    const int G = lane >> 4;
    const int tok = tid >> 6;
    const int nglob = blockIdx.x * TOKW + tok;
    const int b = nglob >> 12;
    const int t = nglob & (TT - 1);
    const int asw = (li & 7) << 4;

    char* xgT = L + tok * 8192;
    char* qT  = xgT + 2048;
    char* kT  = xgT + 4096;
    char* vT  = xgT + 6144;                     // V^T: 64 c x 32B

    {
        int r16 = lane >> 2, part = lane & 3;
        int j = idx[t * NHH + r16];
        const uint4* sp = reinterpret_cast<const uint4*>(xnb + ((size_t)b * TT + j) * MDD + part * 16);
        uint4 w0 = sp[0], w1 = sp[1];
        int sw = (r16 & 7) << 4;
        *reinterpret_cast<uint4*>(xgT + r16 * 128 + ((part * 32) ^ sw)) = w0;
        *reinterpret_cast<uint4*>(xgT + r16 * 128 + ((part * 32 + 16) ^ sw)) = w1;
    }

    bf16x8 xf0 = *reinterpret_cast<const bf16x8*>(xgT + li * 128 + ((G * 16) ^ asw));
    bf16x8 xf1 = *reinterpret_cast<const bf16x8*>(xgT + li * 128 + ((64 + G * 16) ^ asw));
    f32x4 acc[12];
    #pragma unroll
    for (int mt = 0; mt < 12; ++mt) {
        bf16x8 w0 = *reinterpret_cast<const bf16x8*>(Wall + (mt * 2 + 0) * 512 + lane * 8);
        bf16x8 w1 = *reinterpret_cast<const bf16x8*>(Wall + (mt * 2 + 1) * 512 + lane * 8);
        f32x4 a = (f32x4){0.0f, 0.0f, 0.0f, 0.0f};
        a = __builtin_amdgcn_mfma_f32_16x16x32_bf16(w0, xf0, a, 0, 0, 0);
        a = __builtin_amdgcn_mfma_f32_16x16x32_bf16(w1, xf1, a, 0, 0, 0);
        acc[mt] = a;
    }

    float4 bias4[4];
    #pragma unroll
    for (int h = 0; h < 4; ++h)
        bias4[h] = *reinterpret_cast<const float4*>(bias + ((size_t)t * 4 + h) * 256 + li * 16 + G * 4);
    bf16x8 wo0[4], wo1[4];
    #pragma unroll
    for (int mt = 0; mt < 4; ++mt) {
        wo0[mt] = *reinterpret_cast<const bf16x8*>(Wall + (24 + mt * 2 + 0) * 512 + lane * 8);
        wo1[mt] = *reinterpret_cast<const bf16x8*>(Wall + (24 + mt * 2 + 1) * 512 + lane * 8);
    }
    float lsa[4] = {ls[0], ls[1], ls[2], ls[3]};

    #pragma unroll
    for (int h = 0; h < 4; ++h) {
        float4 b4 = *reinterpret_cast<const float4*>(bq + h * 16 + G * 4);
        float q0 = acc[h][0] + b4.x, q1 = acc[h][1] + b4.y, q2 = acc[h][2] + b4.z, q3 = acc[h][3] + b4.w;
        float sq = q0 * q0 + q1 * q1 + q2 * q2 + q3 * q3;
        sq += __shfl_xor(sq, 16); sq += __shfl_xor(sq, 32);
        float iq = 1.0f / fmaxf(sqrtf(sq), 1e-6f);
        uint2 u; u.x = pk2(q0 * iq, q1 * iq); u.y = pk2(q2 * iq, q3 * iq);
        *reinterpret_cast<uint2*>(qT + li * 128 + ((h * 32 + G * 8) ^ asw)) = u;
    }
    #pragma unroll
    for (int h = 0; h < 4; ++h) {
        float4 b4 = *reinterpret_cast<const float4*>(bk + h * 16 + G * 4);
        float k0 = acc[4 + h][0] + b4.x, k1 = acc[4 + h][1] + b4.y, k2 = acc[4 + h][2] + b4.z, k3 = acc[4 + h][3] + b4.w;
        float sk = k0 * k0 + k1 * k1 + k2 * k2 + k3 * k3;
        sk += __shfl_xor(sk, 16); sk += __shfl_xor(sk, 32);
        float ik = 1.0f / fmaxf(sqrtf(sk), 1e-6f);
        uint2 u; u.x = pk2(k0 * ik, k1 * ik); u.y = pk2(k2 * ik, k3 * ik);
        *reinterpret_cast<uint2*>(kT + li * 128 + ((h * 32 + G * 8) ^ asw)) = u;
    }
    #pragma unroll
    for (int m2 = 0; m2 < 4; ++m2) {
        float4 b4 = *reinterpret_cast<const float4*>(bv + m2 * 16 + G * 4);
        float v0 = acc[8 + m2][0] + b4.x, v1 = acc[8 + m2][1] + b4.y, v2 = acc[8 + m2][2] + b4.z, v3 = acc[8 + m2][3] + b4.w;
        int c0 = m2 * 16 + G * 4;
        *reinterpret_cast<unsigned short*>(vT + (c0 + 0) * 32 + li * 2) = f2bf(v0);
        *reinterpret_cast<unsigned short*>(vT + (c0 + 1) * 32 + li * 2) = f2bf(v1);
        *reinterpret_cast<unsigned short*>(vT + (c0 + 2) * 32 + li * 2) = f2bf(v2);
        *reinterpret_cast<unsigned short*>(vT + (c0 + 3) * 32 + li * 2) = f2bf(v3);
    }

    #pragma unroll
    for (int h = 0; h < 4; ++h) {
        bf16x8 kf8 = {}, qf8 = {};
        if (G < 2) {
            kf8 = *reinterpret_cast<const bf16x8*>(kT + li * 128 + ((h * 32 + G * 16) ^ asw));
            qf8 = *reinterpret_cast<const bf16x8*>(qT + li * 128 + ((h * 32 + G * 16) ^ asw));
        }
        f32x4 s4 = __builtin_amdgcn_mfma_f32_16x16x32_bf16(kf8, qf8, (f32x4){0.0f, 0.0f, 0.0f, 0.0f}, 0, 0, 0);
        float sch = __expf(fminf(lsa[h], 4.60517018598809136804f));
        float a0 = s4[0] * sch + bias4[h].x;
        float a1 = s4[1] * sch + bias4[h].y;
        float a2 = s4[2] * sch + bias4[h].z;
        float a3 = s4[3] * sch + bias4[h].w;
        float mx = fmaxf(fmaxf(a0, a1), fmaxf(a2, a3));
        mx = fmaxf(mx, __shfl_xor(mx, 16));
        mx = fmaxf(mx, __shfl_xor(mx, 32));
        float e0 = __expf(a0 - mx), e1 = __expf(a1 - mx), e2 = __expf(a2 - mx), e3 = __expf(a3 - mx);
        float sm = e0 + e1 + e2 + e3;
        sm += __shfl_xor(sm, 16);
        sm += __shfl_xor(sm, 32);
        float inv = 1.0f / sm;
        e0 *= inv; e1 *= inv; e2 *= inv; e3 *= inv;
        unsigned p01 = pk2(e0, e1), p23 = pk2(e2, e3);
        int s0l = li + 32 * (G & 1);
        uint4 pw;
        pw.x = (unsigned)__shfl((int)p01, s0l);
        pw.y = (unsigned)__shfl((int)p23, s0l);
        pw.z = (unsigned)__shfl((int)p01, s0l + 16);
        pw.w = (unsigned)__shfl((int)p23, s0l + 16);
        if (G >= 2) { pw.x = 0; pw.y = 0; pw.z = 0; pw.w = 0; }
        bf16x8 vf8 = {};
        if (G < 2) vf8 = *reinterpret_cast<const bf16x8*>(vT + (h * 16 + li) * 32 + G * 16);
        f32x4 pv = __builtin_amdgcn_mfma_f32_16x16x32_bf16(vf8, __builtin_bit_cast(bf16x8, pw),
                                                           (f32x4){0.0f, 0.0f, 0.0f, 0.0f}, 0, 0, 0);
        uint2 u; u.x = pk2(pv[0], pv[1]); u.y = pk2(pv[2], pv[3]);
        *reinterpret_cast<uint2*>(qT + li * 128 + ((h * 32 + G * 8) ^ asw)) = u;
    }

    float xfn[4][4];
    float rowadd;
    {
        bf16x8 av0 = *reinterpret_cast<const bf16x8*>(qT + li * 128 + ((G * 16) ^ asw));
        bf16x8 av1 = *reinterpret_cast<const bf16x8*>(qT + li * 128 + ((64 + G * 16) ^ asw));
        f32x4 oac[4];
        #pragma unroll
        for (int mt = 0; mt < 4; ++mt) {
            f32x4 a = (f32x4){0.0f, 0.0f, 0.0f, 0.0f};
            a = __builtin_amdgcn_mfma_f32_16x16x32_bf16(wo0[mt], av0, a, 0, 0, 0);
            a = __builtin_amdgcn_mfma_f32_16x16x32_bf16(wo1[mt], av1, a, 0, 0, 0);
            oac[mt] = a;
        }
        float xf[4][4];
        float s = 0.0f, sq = 0.0f;
        #pragma unroll
        for (int mt = 0; mt < 4; ++mt) {
            float4 bo4 = *reinterpret_cast<const float4*>(bo + mt * 16 + G * 4);
            uint2 xg2 = *reinterpret_cast<const uint2*>(xgT + li * 128 + ((mt * 32 + G * 8) ^ asw));
            float r0 = bf2f((unsigned short)(xg2.x & 0xffffu));
            float r1 = bf2f((unsigned short)(xg2.x >> 16));
            float r2 = bf2f((unsigned short)(xg2.y & 0xffffu));
            float r3 = bf2f((unsigned short)(xg2.y >> 16));
            xf[mt][0] = oac[mt][0] + bo4.x + r0;
            xf[mt][1] = oac[mt][1] + bo4.y + r1;
            xf[mt][2] = oac[mt][2] + bo4.z + r2;
            xf[mt][3] = oac[mt][3] + bo4.w + r3;
            #pragma unroll
            for (int r = 0; r < 4; ++r) { s += xf[mt][r]; sq += xf[mt][r] * xf[mt][r]; }
        }
        s += __shfl_xor(s, 16); s += __shfl_xor(s, 32);
        sq += __shfl_xor(sq, 16); sq += __shfl_xor(sq, 32);
        float m = s * (1.0f / 64.0f);
        float var = sq * (1.0f / 64.0f) - m * m;
        float inv = 1.0f / sqrtf(var + 1e-5f);
        #pragma unroll
        for (int mt = 0; mt < 4; ++mt) {
            float4 g24 = *reinterpret_cast<const float4*>(g2 + mt * 16 + G * 4);
            float4 be24 = *reinterpret_cast<const float4*>(be2 + mt * 16 + G * 4);
            xfn[mt][0] = (xf[mt][0] - m) * inv * g24.x + be24.x;
            xfn[mt][1] = (xf[mt][1] - m) * inv * g24.y + be24.y;
            xfn[mt][2] = (xf[mt][2] - m) * inv * g24.z + be24.z;
            xfn[mt][3] = (xf[mt][3] - m) * inv * g24.w + be24.w;
            uint2 u; u.x = pk2(xfn[mt][0], xfn[mt][1]); u.y = pk2(xfn[mt][2], xfn[mt][3]);
            *reinterpret_cast<uint2*>(kT + li * 128 + ((mt * 32 + G * 8) ^ asw)) = u;
        }
    }

    {
        bf16x8 xn0 = *reinterpret_cast<const bf16x8*>(kT + li * 128 + ((G * 16) ^ asw));
        bf16x8 xn1 = *reinterpret_cast<const bf16x8*>(kT + li * 128 + ((64 + G * 16) ^ asw));
        float dot = 0.0f;
        #pragma unroll
        for (int mt = 0; mt < 16; ++mt) {
            bf16x8 w0 = *reinterpret_cast<const bf16x8*>(Wall + (32 + mt * 2 + 0) * 512 + lane * 8);
            bf16x8 w1 = *reinterpret_cast<const bf16x8*>(Wall + (32 + mt * 2 + 1) * 512 + lane * 8);
            f32x4 a = (f32x4){0.0f, 0.0f, 0.0f, 0.0f};
            a = __builtin_amdgcn_mfma_f32_16x16x32_bf16(w0, xn0, a, 0, 0, 0);
            a = __builtin_amdgcn_mfma_f32_16x16x32_bf16(w1, xn1, a, 0, 0, 0);
            float4 bn14 = *reinterpret_cast<const float4*>(bn1 + mt * 16 + G * 4);
            float4 w24 = *reinterpret_cast<const float4*>(Wn2 + mt * 16 + G * 4);
            dot += lrelu(a[0] + bn14.x) * w24.x;
            dot += lrelu(a[1] + bn14.y) * w24.y;
            dot += lrelu(a[2] + bn14.z) * w24.z;
            dot += lrelu(a[3] + bn14.w) * w24.w;
        }
        dot += __shfl_xor(dot, 16);
        dot += __shfl_xor(dot, 32);
        rowadd = lrelu(dot + bn2[0]);
    }

    {
        float s = 0.0f, sq = 0.0f;
        float vals[4][4];
        #pragma unroll
        for (int mt = 0; mt < 4; ++mt)
            #pragma unroll
            for (int r = 0; r < 4; ++r) {
                float v = xfn[mt][r] + rowadd;
                vals[mt][r] = v;
                s += v; sq += v * v;
            }
        s += __shfl_xor(s, 1); s += __shfl_xor(s, 2); s += __shfl_xor(s, 4);
        s += __shfl_xor(s, 8); s += __shfl_xor(s, 16); s += __shfl_xor(s, 32);
        sq += __shfl_xor(sq, 1); sq += __shfl_xor(sq, 2); sq += __shfl_xor(sq, 4);
        sq += __shfl_xor(sq, 8); sq += __shfl_xor(sq, 16); sq += __shfl_xor(sq, 32);
        float m = s * (1.0f / 1024.0f);
        float var = sq * (1.0f / 1024.0f) - m * m;
        float inv = 1.0f / sqrtf(var + 1e-5f);
        int swm = nglob & 7;
        #pragma unroll
        for (int mt = 0; mt < 4; ++mt) {
            int o0 = li * 64 + mt * 16 + G * 4;
            float4 g34 = *reinterpret_cast<const float4*>(g3 + o0);
            float4 be34 = *reinterpret_cast<const float4*>(be3 + o0);
            float u0 = (vals[mt][0] - m) * inv * g34.x + be34.x;
            float u1 = (vals[mt][1] - m) * inv * g34.y + be34.y;
            float u2 = (vals[mt][2] - m) * inv * g34.z + be34.z;
            float u3 = (vals[mt][3] - m) * inv * g34.w + be34.w;
            uint2 u; u.x = pk2(u0, u1); u.y = pk2(u2, u3);
            size_t p = (size_t)nglob * 1024 + li * 64
                     + ((((mt * 2 + (G >> 1)) ^ swm) << 3) | ((G & 1) * 4));
            *reinterpret_cast<uint2*>(xu + p) = u;
        }
    }
}

// ---------------- Kernel 5b: MFMA GEMM, counted-vmcnt double-buffered pipeline ----------------
__global__ __launch_bounds__(256) void k_gemm(const unsigned short* __restrict__ xu,
                                              const unsigned short* __restrict__ Wt,
                                              const float* __restrict__ bu1,
                                              const float* __restrict__ Wu2,
                                              float* __restrict__ partial) {
    int bm = blockIdx.x;          // 0..255
    int bn = blockIdx.y;          // 0..7
    int tid = threadIdx.x;
    int w = tid >> 6, l = tid & 63;
    int wm = w >> 1, wn = w & 1;
    int lr = l & 15, lg = l >> 4;

    __shared__ __align__(1024) unsigned short LB[4 * BMt * BKt];   // 64 KB
    __shared__ float rowpart[2][BMt];
    char* base = reinterpret_cast<char*>(LB);

    f32x4 acc[4][4];
    #pragma unroll
    for (int i = 0; i < 4; ++i)
        #pragma unroll
        for (int j = 0; j < 4; ++j)
            acc[i][j] = (f32x4){0.0f, 0.0f, 0.0f, 0.0f};

    const size_t arow = (size_t)(bm * BMt) * GK;
    const size_t brow = (size_t)(bn * BNt) * GK;

    #define STAGE(kt, buf)                                                            \
        {                                                                             \
            char* Ab_ = base + (buf) * 32768;                                         \
            char* Bb_ = Ab_ + 16384;                                                  \
            int k0_ = (kt) * BKt;                                                     \
            _Pragma("unroll")                                                         \
            for (int p = 0; p < 4; ++p) {                                             \
                int seg = w * 4 + p;                                                  \
                int rl = seg * 8 + (l >> 3);                                          \
                gload16(xu + arow + (size_t)rl * GK + k0_ + (l & 7) * 8, Ab_ + seg * 1024); \
                gload16(Wt + brow + (size_t)rl * GK + k0_ + (l & 7) * 8, Bb_ + seg * 1024); \
            }                                                                         \
        }

    STAGE(0, 0)

    for (int kt = 0; kt < GK / BKt; ++kt) {
        int buf = kt & 1;
        if (kt < GK / BKt - 1) {
            STAGE(kt + 1, buf ^ 1)
            asm volatile("s_waitcnt vmcnt(8)" ::: "memory");
        } else {
            asm volatile("s_waitcnt vmcnt(0)" ::: "memory");
        }
        __builtin_amdgcn_sched_barrier(0);
        __builtin_amdgcn_s_barrier();
        __builtin_amdgcn_sched_barrier(0);
        char* Ab = base + buf * 32768;
        char* Bb = Ab + 16384;
        #pragma unroll
        for (int ks = 0; ks < 2; ++ks) {
            bf16x8 af[4], bfr[4];
            #pragma unroll
            for (int rf = 0; rf < 4; ++rf) {
                int row = wm * 64 + rf * 16 + lr;
                int coff = (ks * 64 + lg * 16) ^ ((row & 7) << 4);
                af[rf] = *reinterpret_cast<const bf16x8*>(Ab + row * 128 + coff);
            }
            #pragma unroll
            for (int nf = 0; nf < 4; ++nf) {
                int rowb = wn * 64 + nf * 16 + lr;
                int coff = (ks * 64 + lg * 16) ^ ((rowb & 7) << 4);
                bfr[nf] = *reinterpret_cast<const bf16x8*>(Bb + rowb * 128 + coff);
            }
            #pragma unroll
            for (int rf = 0; rf < 4; ++rf)
                #pragma unroll
                for (int nf = 0; nf < 4; ++nf)
                    acc[rf][nf] = __builtin_amdgcn_mfma_f32_16x16x32_bf16(af[rf], bfr[nf], acc[rf][nf], 0, 0, 0);
        }
        __builtin_amdgcn_sched_barrier(0);
        __builtin_amdgcn_s_barrier();
    }
    #undef STAGE

    float b1v[4], w2v[4];
    #pragma unroll
    for (int nf = 0; nf < 4; ++nf) {
        int nn = bn * BNt + wn * 64 + nf * 16 + lr;
        b1v[nf] = bu1[nn];
        w2v[nf] = Wu2[nn];
    }
    float rowsum[4][4];
    #pragma unroll
    for (int rf = 0; rf < 4; ++rf) {
        #pragma unroll
        for (int j = 0; j < 4; ++j) {
            float s = 0.0f;
            #pragma unroll
            for (int nf = 0; nf < 4; ++nf)
                s += lrelu(acc[rf][nf][j] + b1v[nf]) * w2v[nf];
            #pragma unroll
            for (int off = 1; off < 16; off <<= 1)
                s += __shfl_xor(s, off);
            rowsum[rf][j] = s;
        }
    }
    if (lr == 0) {
        #pragma unroll
        for (int rf = 0; rf < 4; ++rf)
            #pragma unroll
            for (int j = 0; j < 4; ++j)
                rowpart[wn][wm * 64 + rf * 16 + lg * 4 + j] = rowsum[rf][j];
    }
    __syncthreads();
    if (tid < BMt) {
        float v = rowpart[0][tid] + rowpart[1][tid];
        partial[((size_t)(bm * BMt + tid)) * NCHUNK + bn] = v;
    }
}

// ---------------- Kernel 5c: sum partials + bias + lrelu ----------------
__global__ __launch_bounds__(256) void k_reduce(const float* __restrict__ partial,
                                                const float* __restrict__ bu2,
                                                float* __restrict__ out) {
    int m = blockIdx.x * 256 + threadIdx.x;
    float s = bu2[0];
    #pragma unroll
    for (int c = 0; c < NCHUNK; ++c) s += partial[(size_t)m * NCHUNK + c];
    out[m] = lrelu(s);
}

extern "C" void kernel_launch(void* const* d_in, const int* in_sizes, int n_in,
                              void* d_out, int out_size, void* d_ws, size_t ws_size,
                              hipStream_t stream) {
    const float* x   = (const float*)d_in[0];
    const float* c1  = (const float*)d_in[1];
    const float* c2  = (const float*)d_in[2];
    const float* g1  = (const float*)d_in[3];
    const float* be1 = (const float*)d_in[4];
    const float* Wq  = (const float*)d_in[5];
    const float* bq  = (const float*)d_in[6];
    const float* Wk  = (const float*)d_in[7];
    const float* bk  = (const float*)d_in[8];
    const float* Wv  = (const float*)d_in[9];
    const float* bv  = (const float*)d_in[10];
    const float* ls  = (const float*)d_in[11];
    const float* Wo  = (const float*)d_in[12];
    const float* bo  = (const float*)d_in[13];
    const float* Wp1 = (const float*)d_in[14];
    const float* bp1 = (const float*)d_in[15];
    const float* Wp2 = (const float*)d_in[16];
    const float* bp2 = (const float*)d_in[17];
    const float* g2  = (const float*)d_in[18];
    const float* be2 = (const float*)d_in[19];
    const float* Wn1 = (const float*)d_in[20];
    const float* bn1 = (const float*)d_in[21];
    const float* Wn2 = (const float*)d_in[22];
    const float* bn2 = (const float*)d_in[23];
    const float* g3  = (const float*)d_in[24];
    const float* be3 = (const float*)d_in[25];
    const float* Wu1 = (const float*)d_in[26];
    const float* bu1 = (const float*)d_in[27];
    const float* Wu2 = (const float*)d_in[28];
    const float* bu2 = (const float*)d_in[29];
    float* out = (float*)d_out;

    char* ws = (char*)d_ws;
    size_t off = 0;
    int*   idx  = (int*)(ws + off);   off += (size_t)TT * NHH * 4;
    float* c1n  = (float*)(ws + off); off += (size_t)TT * NHH * 4;
    float* c2n  = (float*)(ws + off); off += (size_t)TT * NHH * 4;
    float* bias = (float*)(ws + off); off += (size_t)TT * HEADSS * NHH * NHH * 4;   // 16 MB
    unsigned short* xnb  = (unsigned short*)(ws + off); off += (size_t)BB * TT * MDD * 2;   // 4 MB
    unsigned short* xuB  = (unsigned short*)(ws + off); off += (size_t)GM * GK * 2;         // 64 MB
    unsigned short* Wu1t = (unsigned short*)(ws + off); off += (size_t)GK * GN * 2;         // 2 MB
    float* partial = (float*)(ws + off); off += (size_t)GM * NCHUNK * 4;                    // 1 MB
    unsigned short* Wall = (unsigned short*)(ws + off); off += 64 * 1024;                   // 64 KB

    k_front<<<TT + (BB * TT) / 4 + 128 + 1024, 256, 0, stream>>>(
        c1, c2, Wp1, bp1, Wp2, bp2, idx, c1n, c2n, bias,
        x, g1, be1, xnb, Wq, Wk, Wv, Wo, Wn1, Wall, Wu1, Wu1t);
    k_main<<<(BB * TT) / TOKW, 256, 0, stream>>>(xnb, idx, bias, Wall,
                                                 bq, bk, bv, ls, bo, g2, be2, bn1, Wn2, bn2, g3, be3, xuB);
    k_gemm<<<dim3(GM / BMt, GN / BNt), 256, 0, stream>>>(xuB, Wu1t, bu1, Wu2, partial);
    k_reduce<<<GM / 256, 256, 0, stream>>>(partial, bu2, out);
}

// Round 16
// 321.223 us; speedup vs baseline: 1.0525x; 1.0525x over previous
//
#include <hip/hip_runtime.h>
#include <hip/hip_bf16.h>

#define BB 8
#define TT 4096
#define NHH 16
#define MDD 64
#define FFF 256
#define HEADSS 4
#define DHH 16
#define PEHH 32

#define GM (BB * TT)      // 32768
#define GK 1024
#define GN 1024
#define BMt 128
#define BNt 128
#define BKt 64
#define NCHUNK (GN / BNt) // 8

#define TOKW 4            // tokens per k_main block (1 wave each)

typedef float f32x4 __attribute__((ext_vector_type(4)));
typedef short bf16x8 __attribute__((ext_vector_type(8)));

static __device__ __forceinline__ float lrelu(float x) { return x > 0.0f ? x : 0.2f * x; }
static __device__ __forceinline__ unsigned long long umin64(unsigned long long a, unsigned long long b) {
    return a < b ? a : b;
}
static __device__ __forceinline__ unsigned short f2bf(float f) {
    __bf16 b = (__bf16)f;                       // native RNE cvt; pairs fuse to v_cvt_pk_bf16_f32
    return __builtin_bit_cast(unsigned short, b);
}
static __device__ __forceinline__ float bf2f(unsigned short u) {
    return __uint_as_float(((unsigned)u) << 16);
}
static __device__ __forceinline__ unsigned pk2(float a, float b) {
    return (unsigned)f2bf(a) | ((unsigned)f2bf(b) << 16);
}
static __device__ __forceinline__ void gload16(const void* g, void* l) {
    __builtin_amdgcn_global_load_lds((const __attribute__((address_space(1))) unsigned int*)g,
                                     (__attribute__((address_space(3))) unsigned int*)l, 16, 0, 0);
}

// ---------------- Kernel 1: fused front (NN-search+bias | LN1 | Wall pack | Wu1 transpose) ----
__global__ __launch_bounds__(256) void k_front(const float* __restrict__ c1,
                                               const float* __restrict__ c2,
                                               const float* __restrict__ Wp1,
                                               const float* __restrict__ bp1,
                                               const float* __restrict__ Wp2,
                                               const float* __restrict__ bp2,
                                               int* __restrict__ idx,
                                               float* __restrict__ c1n,
                                               float* __restrict__ c2n,
                                               float* __restrict__ bias,
                                               const float* __restrict__ x,
                                               const float* __restrict__ g1,
                                               const float* __restrict__ be1,
                                               unsigned short* __restrict__ xn,
                                               const float* __restrict__ Wq, const float* __restrict__ Wk,
                                               const float* __restrict__ Wv, const float* __restrict__ Wo,
                                               const float* __restrict__ Wn1,
                                               unsigned short* __restrict__ Wall,
                                               const float* __restrict__ W,
                                               unsigned short* __restrict__ Wt) {
    int blk = blockIdx.x;
    int tid = threadIdx.x;
    if (blk < TT) {
        int t = blk;
        int lane = tid & 63, w = tid >> 6;
        __shared__ unsigned long long stage[4 * NHH];
        __shared__ float sc1[NHH], sc2[NHH];
        __shared__ float sWp1[2 * PEHH], sbp1[PEHH], sWp2[PEHH * HEADSS], sbp2[HEADSS];
        if (tid < 2 * PEHH) sWp1[tid] = Wp1[tid];
        if (tid < PEHH) sbp1[tid] = bp1[tid];
        if (tid < PEHH * HEADSS) sWp2[tid] = Wp2[tid];
        if (tid < HEADSS) sbp2[tid] = bp2[tid];
        float c1t = c1[t], c2t = c2[t];

        unsigned long long keys[16];
        #pragma unroll
        for (int i = 0; i < 16; ++i) {
            int j = i * 256 + tid;
            float d1 = __fsub_rn(c1[j], c1t);
            float d2 = __fsub_rn(c2[j], c2t);
            float dist = __fadd_rn(__fmul_rn(d1, d1), __fmul_rn(d2, d2));
            keys[i] = (((unsigned long long)__float_as_uint(dist)) << 32) | (unsigned)j;
        }

        #pragma unroll 1
        for (int s = 0; s < NHH; ++s) {
            unsigned long long m = keys[0];
            #pragma unroll
            for (int i = 1; i < 16; ++i) m = umin64(m, keys[i]);
            #pragma unroll
            for (int off = 1; off < 64; off <<= 1)
                m = umin64(m, (unsigned long long)__shfl_xor((long long)m, off));
            #pragma unroll
            for (int i = 0; i < 16; ++i)
                if (keys[i] == m) keys[i] = ~0ull;
            if (lane == 0) stage[w * NHH + s] = m;
        }
        __syncthreads();

        if (w == 0) {
            unsigned long long k0 = stage[lane];
            #pragma unroll 1
            for (int s = 0; s < NHH; ++s) {
                unsigned long long m = k0;
                #pragma unroll
                for (int off = 1; off < 64; off <<= 1)
                    m = umin64(m, (unsigned long long)__shfl_xor((long long)m, off));
                if (k0 == m) k0 = ~0ull;
                if (lane == 0) {
                    int jj = (int)(unsigned)(m & 0xffffffffu);
                    float v1 = __fsub_rn(c1[jj], c1t);
                    float v2 = __fsub_rn(c2[jj], c2t);
                    idx[t * NHH + s] = jj;
                    c1n[t * NHH + s] = v1;
                    c2n[t * NHH + s] = v2;
                    sc1[s] = v1;
                    sc2[s] = v2;
                }
            }
        }
        __syncthreads();

        {
            int j = tid & 15, i = tid >> 4;
            float p1 = sc1[i] - sc1[j];
            float p2 = sc2[i] - sc2[j];
            float acc0 = sbp2[0], acc1 = sbp2[1], acc2 = sbp2[2], acc3 = sbp2[3];
            #pragma unroll
            for (int kk = 0; kk < PEHH; ++kk) {
                float h = lrelu(p1 * sWp1[kk] + p2 * sWp1[PEHH + kk] + sbp1[kk]);
                acc0 += h * sWp2[kk * HEADSS + 0];
                acc1 += h * sWp2[kk * HEADSS + 1];
                acc2 += h * sWp2[kk * HEADSS + 2];
                acc3 += h * sWp2[kk * HEADSS + 3];
            }
            float* bt = bias + (size_t)t * HEADSS * NHH * NHH;
            bt[0 * 256 + i * NHH + j] = acc0;
            bt[1 * 256 + i * NHH + j] = acc1;
            bt[2 * 256 + i * NHH + j] = acc2;
            bt[3 * 256 + i * NHH + j] = acc3;
        }
        return;
    }
    blk -= TT;
    if (blk < (BB * TT) / 4) {
        int row = blk * 4 + (tid >> 6);
        int lane = tid & 63;
        float v = x[(size_t)row * MDD + lane];
        float s = v;
        for (int off = 32; off > 0; off >>= 1) s += __shfl_down(s, off);
        s = __shfl(s, 0);
        float m = s * (1.0f / 64.0f);
        float d = v - m;
        float sq = d * d;
        for (int off = 32; off > 0; off >>= 1) sq += __shfl_down(sq, off);
        sq = __shfl(sq, 0);
        float var = sq * (1.0f / 64.0f);
        float inv = 1.0f / sqrtf(var + 1e-5f);
        xn[(size_t)row * MDD + lane] = f2bf(d * inv * g1[lane] + be1[lane]);
        return;
    }
    blk -= (BB * TT) / 4;
    if (blk < 128) {
        int id = blk * 256 + tid;
        int f = id >> 9;
        int wv = (id >> 3) & 63;
        int e = id & 7;
        int li = wv & 15, G = wv >> 4;
        float v;
        if (f < 24) {
            int mt = f >> 1, ks = f & 1;
            int n = mt * 16 + li;
            int k = ks * 32 + G * 8 + e;
            v = (n < 64) ? Wq[k * 64 + n] : (n < 128) ? Wk[k * 64 + (n - 64)] : Wv[k * 64 + (n - 128)];
        } else if (f < 32) {
            int g2i = f - 24;
            int mt = g2i >> 1, ks = g2i & 1;
            int n = mt * 16 + li;
            int k = ks * 32 + G * 8 + e;
            v = Wo[k * 64 + n];
        } else {
            int g2i = f - 32;
            int mt = g2i >> 1, ks = g2i & 1;
            int n = mt * 16 + li;
            int k = ks * 32 + G * 8 + e;
            v = Wn1[k * 256 + n];
        }
        Wall[id] = f2bf(v);
        return;
    }
    blk -= 128;
    {
        __shared__ float tile[32][33];
        int tk = blk & 31;
        int tn = blk >> 5;
        int c = tid & 31, r4 = tid >> 5;
        #pragma unroll
        for (int p = 0; p < 4; ++p) {
            int r = p * 8 + r4;
            tile[r][c] = W[(size_t)(tk * 32 + r) * GN + tn * 32 + c];
        }
        __syncthreads();
        #pragma unroll
        for (int p = 0; p < 4; ++p) {
            int r = p * 8 + r4;
            int n = tn * 32 + r;
            int kk = tk * 32 + c;
            int chunk = kk >> 6, slot = (kk >> 3) & 7, e = kk & 7;
            Wt[(size_t)n * GK + chunk * 64 + ((slot ^ (n & 7)) << 3) + e] = f2bf(tile[c][r]);
        }
    }
}

// ---------------- Kernel 4: fused block kernel, weights from L2, zero barriers ----------------
__global__ __launch_bounds__(256, 4) void k_main(const unsigned short* __restrict__ xnb,
                                              const int* __restrict__ idx,
                                              const float* __restrict__ bias,
                                              const unsigned short* __restrict__ Wall,
                                              const float* __restrict__ bq, const float* __restrict__ bk,
                                              const float* __restrict__ bv, const float* __restrict__ ls,
                                              const float* __restrict__ bo,
                                              const float* __restrict__ g2, const float* __restrict__ be2,
                                              const float* __restrict__ bn1, const float* __restrict__ Wn2,
                                              const float* __restrict__ bn2,
                                              const float* __restrict__ g3, const float* __restrict__ be3,
                                              unsigned short* __restrict__ xu) {
    __shared__ __align__(16) char L[TOKW * 8192];   // 32 KB
    const int tid = threadIdx.x;
    const int lane = tid & 63;
    const int li = lane & 15;
    const int G = lane >> 4;
    const int tok = tid >> 6;
    const int nglob = blockIdx.x * TOKW + tok;
    const int b = nglob >> 12;
    const int t = nglob & (TT - 1);
    const int asw = (li & 7) << 4;

    char* xgT = L + tok * 8192;
    char* qT  = xgT + 2048;
    char* kT  = xgT + 4096;
    char* vT  = xgT + 6144;                     // V^T: 64 c x 32B

    {
        int r16 = lane >> 2, part = lane & 3;
        int j = idx[t * NHH + r16];
        const uint4* sp = reinterpret_cast<const uint4*>(xnb + ((size_t)b * TT + j) * MDD + part * 16);
        uint4 w0 = sp[0], w1 = sp[1];
        int sw = (r16 & 7) << 4;
        *reinterpret_cast<uint4*>(xgT + r16 * 128 + ((part * 32) ^ sw)) = w0;
        *reinterpret_cast<uint4*>(xgT + r16 * 128 + ((part * 32 + 16) ^ sw)) = w1;
    }

    bf16x8 xf0 = *reinterpret_cast<const bf16x8*>(xgT + li * 128 + ((G * 16) ^ asw));
    bf16x8 xf1 = *reinterpret_cast<const bf16x8*>(xgT + li * 128 + ((64 + G * 16) ^ asw));
    f32x4 acc[12];
    #pragma unroll
    for (int mt = 0; mt < 12; ++mt) {
        bf16x8 w0 = *reinterpret_cast<const bf16x8*>(Wall + (mt * 2 + 0) * 512 + lane * 8);
        bf16x8 w1 = *reinterpret_cast<const bf16x8*>(Wall + (mt * 2 + 1) * 512 + lane * 8);
        f32x4 a = (f32x4){0.0f, 0.0f, 0.0f, 0.0f};
        a = __builtin_amdgcn_mfma_f32_16x16x32_bf16(w0, xf0, a, 0, 0, 0);
        a = __builtin_amdgcn_mfma_f32_16x16x32_bf16(w1, xf1, a, 0, 0, 0);
        acc[mt] = a;
    }

    float4 bias4[4];
    #pragma unroll
    for (int h = 0; h < 4; ++h)
        bias4[h] = *reinterpret_cast<const float4*>(bias + ((size_t)t * 4 + h) * 256 + li * 16 + G * 4);
    bf16x8 wo0[4], wo1[4];
    #pragma unroll
    for (int mt = 0; mt < 4; ++mt) {
        wo0[mt] = *reinterpret_cast<const bf16x8*>(Wall + (24 + mt * 2 + 0) * 512 + lane * 8);
        wo1[mt] = *reinterpret_cast<const bf16x8*>(Wall + (24 + mt * 2 + 1) * 512 + lane * 8);
    }
    float lsa[4] = {ls[0], ls[1], ls[2], ls[3]};

    #pragma unroll
    for (int h = 0; h < 4; ++h) {
        float4 b4 = *reinterpret_cast<const float4*>(bq + h * 16 + G * 4);
        float q0 = acc[h][0] + b4.x, q1 = acc[h][1] + b4.y, q2 = acc[h][2] + b4.z, q3 = acc[h][3] + b4.w;
        float sq = q0 * q0 + q1 * q1 + q2 * q2 + q3 * q3;
        sq += __shfl_xor(sq, 16); sq += __shfl_xor(sq, 32);
        float iq = 1.0f / fmaxf(sqrtf(sq), 1e-6f);
        uint2 u; u.x = pk2(q0 * iq, q1 * iq); u.y = pk2(q2 * iq, q3 * iq);
        *reinterpret_cast<uint2*>(qT + li * 128 + ((h * 32 + G * 8) ^ asw)) = u;
    }
    #pragma unroll
    for (int h = 0; h < 4; ++h) {
        float4 b4 = *reinterpret_cast<const float4*>(bk + h * 16 + G * 4);
        float k0 = acc[4 + h][0] + b4.x, k1 = acc[4 + h][1] + b4.y, k2 = acc[4 + h][2] + b4.z, k3 = acc[4 + h][3] + b4.w;
        float sk = k0 * k0 + k1 * k1 + k2 * k2 + k3 * k3;
        sk += __shfl_xor(sk, 16); sk += __shfl_xor(sk, 32);
        float ik = 1.0f / fmaxf(sqrtf(sk), 1e-6f);
        uint2 u; u.x = pk2(k0 * ik, k1 * ik); u.y = pk2(k2 * ik, k3 * ik);
        *reinterpret_cast<uint2*>(kT + li * 128 + ((h * 32 + G * 8) ^ asw)) = u;
    }
    #pragma unroll
    for (int m2 = 0; m2 < 4; ++m2) {
        float4 b4 = *reinterpret_cast<const float4*>(bv + m2 * 16 + G * 4);
        float v0 = acc[8 + m2][0] + b4.x, v1 = acc[8 + m2][1] + b4.y, v2 = acc[8 + m2][2] + b4.z, v3 = acc[8 + m2][3] + b4.w;
        int c0 = m2 * 16 + G * 4;
        *reinterpret_cast<unsigned short*>(vT + (c0 + 0) * 32 + li * 2) = f2bf(v0);
        *reinterpret_cast<unsigned short*>(vT + (c0 + 1) * 32 + li * 2) = f2bf(v1);
        *reinterpret_cast<unsigned short*>(vT + (c0 + 2) * 32 + li * 2) = f2bf(v2);
        *reinterpret_cast<unsigned short*>(vT + (c0 + 3) * 32 + li * 2) = f2bf(v3);
    }

    #pragma unroll
    for (int h = 0; h < 4; ++h) {
        bf16x8 kf8 = {}, qf8 = {};
        if (G < 2) {
            kf8 = *reinterpret_cast<const bf16x8*>(kT + li * 128 + ((h * 32 + G * 16) ^ asw));
            qf8 = *reinterpret_cast<const bf16x8*>(qT + li * 128 + ((h * 32 + G * 16) ^ asw));
        }
        f32x4 s4 = __builtin_amdgcn_mfma_f32_16x16x32_bf16(kf8, qf8, (f32x4){0.0f, 0.0f, 0.0f, 0.0f}, 0, 0, 0);
        float sch = __expf(fminf(lsa[h], 4.60517018598809136804f));
        float a0 = s4[0] * sch + bias4[h].x;
        float a1 = s4[1] * sch + bias4[h].y;
        float a2 = s4[2] * sch + bias4[h].z;
        float a3 = s4[3] * sch + bias4[h].w;
        float mx = fmaxf(fmaxf(a0, a1), fmaxf(a2, a3));
        mx = fmaxf(mx, __shfl_xor(mx, 16));
        mx = fmaxf(mx, __shfl_xor(mx, 32));
        float e0 = __expf(a0 - mx), e1 = __expf(a1 - mx), e2 = __expf(a2 - mx), e3 = __expf(a3 - mx);
        float sm = e0 + e1 + e2 + e3;
        sm += __shfl_xor(sm, 16);
        sm += __shfl_xor(sm, 32);
        float inv = 1.0f / sm;
        e0 *= inv; e1 *= inv; e2 *= inv; e3 *= inv;
        unsigned p01 = pk2(e0, e1), p23 = pk2(e2, e3);
        int s0l = li + 32 * (G & 1);
        uint4 pw;
        pw.x = (unsigned)__shfl((int)p01, s0l);
        pw.y = (unsigned)__shfl((int)p23, s0l);
        pw.z = (unsigned)__shfl((int)p01, s0l + 16);
        pw.w = (unsigned)__shfl((int)p23, s0l + 16);
        if (G >= 2) { pw.x = 0; pw.y = 0; pw.z = 0; pw.w = 0; }
        bf16x8 vf8 = {};
        if (G < 2) vf8 = *reinterpret_cast<const bf16x8*>(vT + (h * 16 + li) * 32 + G * 16);
        f32x4 pv = __builtin_amdgcn_mfma_f32_16x16x32_bf16(vf8, __builtin_bit_cast(bf16x8, pw),
                                                           (f32x4){0.0f, 0.0f, 0.0f, 0.0f}, 0, 0, 0);
        uint2 u; u.x = pk2(pv[0], pv[1]); u.y = pk2(pv[2], pv[3]);
        *reinterpret_cast<uint2*>(qT + li * 128 + ((h * 32 + G * 8) ^ asw)) = u;
    }

    float xfn[4][4];
    float rowadd;
    {
        bf16x8 av0 = *reinterpret_cast<const bf16x8*>(qT + li * 128 + ((G * 16) ^ asw));
        bf16x8 av1 = *reinterpret_cast<const bf16x8*>(qT + li * 128 + ((64 + G * 16) ^ asw));
        f32x4 oac[4];
        #pragma unroll
        for (int mt = 0; mt < 4; ++mt) {
            f32x4 a = (f32x4){0.0f, 0.0f, 0.0f, 0.0f};
            a = __builtin_amdgcn_mfma_f32_16x16x32_bf16(wo0[mt], av0, a, 0, 0, 0);
            a = __builtin_amdgcn_mfma_f32_16x16x32_bf16(wo1[mt], av1, a, 0, 0, 0);
            oac[mt] = a;
        }
        float xf[4][4];
        float s = 0.0f, sq = 0.0f;
        #pragma unroll
        for (int mt = 0; mt < 4; ++mt) {
            float4 bo4 = *reinterpret_cast<const float4*>(bo + mt * 16 + G * 4);
            uint2 xg2 = *reinterpret_cast<const uint2*>(xgT + li * 128 + ((mt * 32 + G * 8) ^ asw));
            float r0 = bf2f((unsigned short)(xg2.x & 0xffffu));
            float r1 = bf2f((unsigned short)(xg2.x >> 16));
            float r2 = bf2f((unsigned short)(xg2.y & 0xffffu));
            float r3 = bf2f((unsigned short)(xg2.y >> 16));
            xf[mt][0] = oac[mt][0] + bo4.x + r0;
            xf[mt][1] = oac[mt][1] + bo4.y + r1;
            xf[mt][2] = oac[mt][2] + bo4.z + r2;
            xf[mt][3] = oac[mt][3] + bo4.w + r3;
            #pragma unroll
            for (int r = 0; r < 4; ++r) { s += xf[mt][r]; sq += xf[mt][r] * xf[mt][r]; }
        }
        s += __shfl_xor(s, 16); s += __shfl_xor(s, 32);
        sq += __shfl_xor(sq, 16); sq += __shfl_xor(sq, 32);
        float m = s * (1.0f / 64.0f);
        float var = sq * (1.0f / 64.0f) - m * m;
        float inv = 1.0f / sqrtf(var + 1e-5f);
        #pragma unroll
        for (int mt = 0; mt < 4; ++mt) {
            float4 g24 = *reinterpret_cast<const float4*>(g2 + mt * 16 + G * 4);
            float4 be24 = *reinterpret_cast<const float4*>(be2 + mt * 16 + G * 4);
            xfn[mt][0] = (xf[mt][0] - m) * inv * g24.x + be24.x;
            xfn[mt][1] = (xf[mt][1] - m) * inv * g24.y + be24.y;
            xfn[mt][2] = (xf[mt][2] - m) * inv * g24.z + be24.z;
            xfn[mt][3] = (xf[mt][3] - m) * inv * g24.w + be24.w;
            uint2 u; u.x = pk2(xfn[mt][0], xfn[mt][1]); u.y = pk2(xfn[mt][2], xfn[mt][3]);
            *reinterpret_cast<uint2*>(kT + li * 128 + ((mt * 32 + G * 8) ^ asw)) = u;
        }
    }

    {
        bf16x8 xn0 = *reinterpret_cast<const bf16x8*>(kT + li * 128 + ((G * 16) ^ asw));
        bf16x8 xn1 = *reinterpret_cast<const bf16x8*>(kT + li * 128 + ((64 + G * 16) ^ asw));
        float dot = 0.0f;
        #pragma unroll
        for (int mt = 0; mt < 16; ++mt) {
            bf16x8 w0 = *reinterpret_cast<const bf16x8*>(Wall + (32 + mt * 2 + 0) * 512 + lane * 8);
            bf16x8 w1 = *reinterpret_cast<const bf16x8*>(Wall + (32 + mt * 2 + 1) * 512 + lane * 8);
            f32x4 a = (f32x4){0.0f, 0.0f, 0.0f, 0.0f};
            a = __builtin_amdgcn_mfma_f32_16x16x32_bf16(w0, xn0, a, 0, 0, 0);
            a = __builtin_amdgcn_mfma_f32_16x16x32_bf16(w1, xn1, a, 0, 0, 0);
            float4 bn14 = *reinterpret_cast<const float4*>(bn1 + mt * 16 + G * 4);
            float4 w24 = *reinterpret_cast<const float4*>(Wn2 + mt * 16 + G * 4);
            dot += lrelu(a[0] + bn14.x) * w24.x;
            dot += lrelu(a[1] + bn14.y) * w24.y;
            dot += lrelu(a[2] + bn14.z) * w24.z;
            dot += lrelu(a[3] + bn14.w) * w24.w;
        }
        dot += __shfl_xor(dot, 16);
        dot += __shfl_xor(dot, 32);
        rowadd = lrelu(dot + bn2[0]);
    }

    {
        float s = 0.0f, sq = 0.0f;
        float vals[4][4];
        #pragma unroll
        for (int mt = 0; mt < 4; ++mt)
            #pragma unroll
            for (int r = 0; r < 4; ++r) {
                float v = xfn[mt][r] + rowadd;
                vals[mt][r] = v;
                s += v; sq += v * v;
            }
        s += __shfl_xor(s, 1); s += __shfl_xor(s, 2); s += __shfl_xor(s, 4);
        s += __shfl_xor(s, 8); s += __shfl_xor(s, 16); s += __shfl_xor(s, 32);
        sq += __shfl_xor(sq, 1); sq += __shfl_xor(sq, 2); sq += __shfl_xor(sq, 4);
        sq += __shfl_xor(sq, 8); sq += __shfl_xor(sq, 16); sq += __shfl_xor(sq, 32);
        float m = s * (1.0f / 1024.0f);
        float var = sq * (1.0f / 1024.0f) - m * m;
        float inv = 1.0f / sqrtf(var + 1e-5f);
        int swm = nglob & 7;
        #pragma unroll
        for (int mt = 0; mt < 4; ++mt) {
            int o0 = li * 64 + mt * 16 + G * 4;
            float4 g34 = *reinterpret_cast<const float4*>(g3 + o0);
            float4 be34 = *reinterpret_cast<const float4*>(be3 + o0);
            float u0 = (vals[mt][0] - m) * inv * g34.x + be34.x;
            float u1 = (vals[mt][1] - m) * inv * g34.y + be34.y;
            float u2 = (vals[mt][2] - m) * inv * g34.z + be34.z;
            float u3 = (vals[mt][3] - m) * inv * g34.w + be34.w;
            uint2 u; u.x = pk2(u0, u1); u.y = pk2(u2, u3);
            size_t p = (size_t)nglob * 1024 + li * 64
                     + ((((mt * 2 + (G >> 1)) ^ swm) << 3) | ((G & 1) * 4));
            *reinterpret_cast<uint2*>(xu + p) = u;
        }
    }
}

// ---------------- Kernel 5b: MFMA GEMM, counted-vmcnt double-buffered pipeline ----------------
__global__ __launch_bounds__(256) void k_gemm(const unsigned short* __restrict__ xu,
                                              const unsigned short* __restrict__ Wt,
                                              const float* __restrict__ bu1,
                                              const float* __restrict__ Wu2,
                                              float* __restrict__ partial) {
    int bm = blockIdx.x;          // 0..255
    int bn = blockIdx.y;          // 0..7
    int tid = threadIdx.x;
    int w = tid >> 6, l = tid & 63;
    int wm = w >> 1, wn = w & 1;
    int lr = l & 15, lg = l >> 4;

    __shared__ __align__(1024) unsigned short LB[4 * BMt * BKt];   // 64 KB
    __shared__ float rowpart[2][BMt];
    char* base = reinterpret_cast<char*>(LB);

    f32x4 acc[4][4];
    #pragma unroll
    for (int i = 0; i < 4; ++i)
        #pragma unroll
        for (int j = 0; j < 4; ++j)
            acc[i][j] = (f32x4){0.0f, 0.0f, 0.0f, 0.0f};

    const size_t arow = (size_t)(bm * BMt) * GK;
    const size_t brow = (size_t)(bn * BNt) * GK;

    #define STAGE(kt, buf)                                                            \
        {                                                                             \
            char* Ab_ = base + (buf) * 32768;                                         \
            char* Bb_ = Ab_ + 16384;                                                  \
            int k0_ = (kt) * BKt;                                                     \
            _Pragma("unroll")                                                         \
            for (int p = 0; p < 4; ++p) {                                             \
                int seg = w * 4 + p;                                                  \
                int rl = seg * 8 + (l >> 3);                                          \
                gload16(xu + arow + (size_t)rl * GK + k0_ + (l & 7) * 8, Ab_ + seg * 1024); \
                gload16(Wt + brow + (size_t)rl * GK + k0_ + (l & 7) * 8, Bb_ + seg * 1024); \
            }                                                                         \
        }

    STAGE(0, 0)

    for (int kt = 0; kt < GK / BKt; ++kt) {
        int buf = kt & 1;
        if (kt < GK / BKt - 1) {
            STAGE(kt + 1, buf ^ 1)
            asm volatile("s_waitcnt vmcnt(8)" ::: "memory");
        } else {
            asm volatile("s_waitcnt vmcnt(0)" ::: "memory");
        }
        __builtin_amdgcn_sched_barrier(0);
        __builtin_amdgcn_s_barrier();
        __builtin_amdgcn_sched_barrier(0);
        char* Ab = base + buf * 32768;
        char* Bb = Ab + 16384;
        #pragma unroll
        for (int ks = 0; ks < 2; ++ks) {
            bf16x8 af[4], bfr[4];
            #pragma unroll
            for (int rf = 0; rf < 4; ++rf) {
                int row = wm * 64 + rf * 16 + lr;
                int coff = (ks * 64 + lg * 16) ^ ((row & 7) << 4);
                af[rf] = *reinterpret_cast<const bf16x8*>(Ab + row * 128 + coff);
            }
            #pragma unroll
            for (int nf = 0; nf < 4; ++nf) {
                int rowb = wn * 64 + nf * 16 + lr;
                int coff = (ks * 64 + lg * 16) ^ ((rowb & 7) << 4);
                bfr[nf] = *reinterpret_cast<const bf16x8*>(Bb + rowb * 128 + coff);
            }
            #pragma unroll
            for (int rf = 0; rf < 4; ++rf)
                #pragma unroll
                for (int nf = 0; nf < 4; ++nf)
                    acc[rf][nf] = __builtin_amdgcn_mfma_f32_16x16x32_bf16(af[rf], bfr[nf], acc[rf][nf], 0, 0, 0);
        }
        __builtin_amdgcn_sched_barrier(0);
        __builtin_amdgcn_s_barrier();
    }
    #undef STAGE

    float b1v[4], w2v[4];
    #pragma unroll
    for (int nf = 0; nf < 4; ++nf) {
        int nn = bn * BNt + wn * 64 + nf * 16 + lr;
        b1v[nf] = bu1[nn];
        w2v[nf] = Wu2[nn];
    }
    float rowsum[4][4];
    #pragma unroll
    for (int rf = 0; rf < 4; ++rf) {
        #pragma unroll
        for (int j = 0; j < 4; ++j) {
            float s = 0.0f;
            #pragma unroll
            for (int nf = 0; nf < 4; ++nf)
                s += lrelu(acc[rf][nf][j] + b1v[nf]) * w2v[nf];
            #pragma unroll
            for (int off = 1; off < 16; off <<= 1)
                s += __shfl_xor(s, off);
            rowsum[rf][j] = s;
        }
    }
    if (lr == 0) {
        #pragma unroll
        for (int rf = 0; rf < 4; ++rf)
            #pragma unroll
            for (int j = 0; j < 4; ++j)
                rowpart[wn][wm * 64 + rf * 16 + lg * 4 + j] = rowsum[rf][j];
    }
    __syncthreads();
    if (tid < BMt) {
        float v = rowpart[0][tid] + rowpart[1][tid];
        partial[((size_t)(bm * BMt + tid)) * NCHUNK + bn] = v;
    }
}

// ---------------- Kernel 5c: sum partials + bias + lrelu ----------------
__global__ __launch_bounds__(256) void k_reduce(const float* __restrict__ partial,
                                                const float* __restrict__ bu2,
                                                float* __restrict__ out) {
    int m = blockIdx.x * 256 + threadIdx.x;
    float s = bu2[0];
    #pragma unroll
    for (int c = 0; c < NCHUNK; ++c) s += partial[(size_t)m * NCHUNK + c];
    out[m] = lrelu(s);
}

extern "C" void kernel_launch(void* const* d_in, const int* in_sizes, int n_in,
                              void* d_out, int out_size, void* d_ws, size_t ws_size,
                              hipStream_t stream) {
    const float* x   = (const float*)d_in[0];
    const float* c1  = (const float*)d_in[1];
    const float* c2  = (const float*)d_in[2];
    const float* g1  = (const float*)d_in[3];
    const float* be1 = (const float*)d_in[4];
    const float* Wq  = (const float*)d_in[5];
    const float* bq  = (const float*)d_in[6];
    const float* Wk  = (const float*)d_in[7];
    const float* bk  = (const float*)d_in[8];
    const float* Wv  = (const float*)d_in[9];
    const float* bv  = (const float*)d_in[10];
    const float* ls  = (const float*)d_in[11];
    const float* Wo  = (const float*)d_in[12];
    const float* bo  = (const float*)d_in[13];
    const float* Wp1 = (const float*)d_in[14];
    const float* bp1 = (const float*)d_in[15];
    const float* Wp2 = (const float*)d_in[16];
    const float* bp2 = (const float*)d_in[17];
    const float* g2  = (const float*)d_in[18];
    const float* be2 = (const float*)d_in[19];
    const float* Wn1 = (const float*)d_in[20];
    const float* bn1 = (const float*)d_in[21];
    const float* Wn2 = (const float*)d_in[22];
    const float* bn2 = (const float*)d_in[23];
    const float* g3  = (const float*)d_in[24];
    const float* be3 = (const float*)d_in[25];
    const float* Wu1 = (const float*)d_in[26];
    const float* bu1 = (const float*)d_in[27];
    const float* Wu2 = (const float*)d_in[28];
    const float* bu2 = (const float*)d_in[29];
    float* out = (float*)d_out;

    char* ws = (char*)d_ws;
    size_t off = 0;
    int*   idx  = (int*)(ws + off);   off += (size_t)TT * NHH * 4;
    float* c1n  = (float*)(ws + off); off += (size_t)TT * NHH * 4;
    float* c2n  = (float*)(ws + off); off += (size_t)TT * NHH * 4;
    float* bias = (float*)(ws + off); off += (size_t)TT * HEADSS * NHH * NHH * 4;   // 16 MB
    unsigned short* xnb  = (unsigned short*)(ws + off); off += (size_t)BB * TT * MDD * 2;   // 4 MB
    unsigned short* xuB  = (unsigned short*)(ws + off); off += (size_t)GM * GK * 2;         // 64 MB
    unsigned short* Wu1t = (unsigned short*)(ws + off); off += (size_t)GK * GN * 2;         // 2 MB
    float* partial = (float*)(ws + off); off += (size_t)GM * NCHUNK * 4;                    // 1 MB
    unsigned short* Wall = (unsigned short*)(ws + off); off += 64 * 1024;                   // 64 KB

    k_front<<<TT + (BB * TT) / 4 + 128 + 1024, 256, 0, stream>>>(
        c1, c2, Wp1, bp1, Wp2, bp2, idx, c1n, c2n, bias,
        x, g1, be1, xnb, Wq, Wk, Wv, Wo, Wn1, Wall, Wu1, Wu1t);
    k_main<<<(BB * TT) / TOKW, 256, 0, stream>>>(xnb, idx, bias, Wall,
                                                 bq, bk, bv, ls, bo, g2, be2, bn1, Wn2, bn2, g3, be3, xuB);
    k_gemm<<<dim3(GM / BMt, GN / BNt), 256, 0, stream>>>(xuB, Wu1t, bu1, Wu2, partial);
    k_reduce<<<GM / 256, 256, 0, stream>>>(partial, bu2, out);
}

// Round 17
// 320.520 us; speedup vs baseline: 1.0548x; 1.0022x over previous
//
#include <hip/hip_runtime.h>
#include <hip/hip_bf16.h>

#define BB 8
#define TT 4096
#define NHH 16
#define MDD 64
#define FFF 256
#define HEADSS 4
#define DHH 16
#define PEHH 32

#define GM (BB * TT)      // 32768
#define GK 1024
#define GN 1024
#define BMt 128
#define BNt 128
#define BKt 64
#define NCHUNK (GN / BNt) // 8

#define TOKW 4            // tokens per k_main block (1 wave each)

typedef float f32x4 __attribute__((ext_vector_type(4)));
typedef short bf16x8 __attribute__((ext_vector_type(8)));

static __device__ __forceinline__ float lrelu(float x) { return x > 0.0f ? x : 0.2f * x; }
static __device__ __forceinline__ unsigned long long umin64(unsigned long long a, unsigned long long b) {
    return a < b ? a : b;
}
static __device__ __forceinline__ unsigned short f2bf(float f) {
    __bf16 b = (__bf16)f;                       // native RNE cvt; pairs fuse to v_cvt_pk_bf16_f32
    return __builtin_bit_cast(unsigned short, b);
}
static __device__ __forceinline__ float bf2f(unsigned short u) {
    return __uint_as_float(((unsigned)u) << 16);
}
static __device__ __forceinline__ unsigned pk2(float a, float b) {
    return (unsigned)f2bf(a) | ((unsigned)f2bf(b) << 16);
}
static __device__ __forceinline__ void gload16(const void* g, void* l) {
    __builtin_amdgcn_global_load_lds((const __attribute__((address_space(1))) unsigned int*)g,
                                     (__attribute__((address_space(3))) unsigned int*)l, 16, 0, 0);
}

// ---------------- Kernel 1: fused front (NN-search+bias | LN1 | Wall pack | Wu1 transpose) ----
__global__ __launch_bounds__(256) void k_front(const float* __restrict__ c1,
                                               const float* __restrict__ c2,
                                               const float* __restrict__ Wp1,
                                               const float* __restrict__ bp1,
                                               const float* __restrict__ Wp2,
                                               const float* __restrict__ bp2,
                                               int* __restrict__ idx,
                                               float* __restrict__ c1n,
                                               float* __restrict__ c2n,
                                               float* __restrict__ bias,
                                               const float* __restrict__ x,
                                               const float* __restrict__ g1,
                                               const float* __restrict__ be1,
                                               unsigned short* __restrict__ xn,
                                               const float* __restrict__ Wq, const float* __restrict__ Wk,
                                               const float* __restrict__ Wv, const float* __restrict__ Wo,
                                               const float* __restrict__ Wn1,
                                               unsigned short* __restrict__ Wall,
                                               const float* __restrict__ W,
                                               unsigned short* __restrict__ Wt) {
    int blk = blockIdx.x;
    int tid = threadIdx.x;
    if (blk < TT) {
        int t = blk;
        int lane = tid & 63, w = tid >> 6;
        __shared__ unsigned long long stage[4 * NHH];
        __shared__ float sc1[NHH], sc2[NHH];
        __shared__ float sWp1[2 * PEHH], sbp1[PEHH], sWp2[PEHH * HEADSS], sbp2[HEADSS];
        if (tid < 2 * PEHH) sWp1[tid] = Wp1[tid];
        if (tid < PEHH) sbp1[tid] = bp1[tid];
        if (tid < PEHH * HEADSS) sWp2[tid] = Wp2[tid];
        if (tid < HEADSS) sbp2[tid] = bp2[tid];
        float c1t = c1[t], c2t = c2[t];

        unsigned long long keys[16];
        #pragma unroll
        for (int i = 0; i < 16; ++i) {
            int j = i * 256 + tid;
            float d1 = __fsub_rn(c1[j], c1t);
            float d2 = __fsub_rn(c2[j], c2t);
            float dist = __fadd_rn(__fmul_rn(d1, d1), __fmul_rn(d2, d2));
            keys[i] = (((unsigned long long)__float_as_uint(dist)) << 32) | (unsigned)j;
        }

        #pragma unroll 1
        for (int s = 0; s < NHH; ++s) {
            unsigned long long m = keys[0];
            #pragma unroll
            for (int i = 1; i < 16; ++i) m = umin64(m, keys[i]);
            #pragma unroll
            for (int off = 1; off < 64; off <<= 1)
                m = umin64(m, (unsigned long long)__shfl_xor((long long)m, off));
            #pragma unroll
            for (int i = 0; i < 16; ++i)
                if (keys[i] == m) keys[i] = ~0ull;
            if (lane == 0) stage[w * NHH + s] = m;
        }
        __syncthreads();

        if (w == 0) {
            unsigned long long k0 = stage[lane];
            #pragma unroll 1
            for (int s = 0; s < NHH; ++s) {
                unsigned long long m = k0;
                #pragma unroll
                for (int off = 1; off < 64; off <<= 1)
                    m = umin64(m, (unsigned long long)__shfl_xor((long long)m, off));
                if (k0 == m) k0 = ~0ull;
                if (lane == 0) {
                    int jj = (int)(unsigned)(m & 0xffffffffu);
                    float v1 = __fsub_rn(c1[jj], c1t);
                    float v2 = __fsub_rn(c2[jj], c2t);
                    idx[t * NHH + s] = jj;
                    c1n[t * NHH + s] = v1;
                    c2n[t * NHH + s] = v2;
                    sc1[s] = v1;
                    sc2[s] = v2;
                }
            }
        }
        __syncthreads();

        {
            int j = tid & 15, i = tid >> 4;
            float p1 = sc1[i] - sc1[j];
            float p2 = sc2[i] - sc2[j];
            float acc0 = sbp2[0], acc1 = sbp2[1], acc2 = sbp2[2], acc3 = sbp2[3];
            #pragma unroll
            for (int kk = 0; kk < PEHH; ++kk) {
                float h = lrelu(p1 * sWp1[kk] + p2 * sWp1[PEHH + kk] + sbp1[kk]);
                acc0 += h * sWp2[kk * HEADSS + 0];
                acc1 += h * sWp2[kk * HEADSS + 1];
                acc2 += h * sWp2[kk * HEADSS + 2];
                acc3 += h * sWp2[kk * HEADSS + 3];
            }
            float* bt = bias + (size_t)t * HEADSS * NHH * NHH;
            bt[0 * 256 + i * NHH + j] = acc0;
            bt[1 * 256 + i * NHH + j] = acc1;
            bt[2 * 256 + i * NHH + j] = acc2;
            bt[3 * 256 + i * NHH + j] = acc3;
        }
        return;
    }
    blk -= TT;
    if (blk < (BB * TT) / 4) {
        int row = blk * 4 + (tid >> 6);
        int lane = tid & 63;
        float v = x[(size_t)row * MDD + lane];
        float s = v;
        for (int off = 32; off > 0; off >>= 1) s += __shfl_down(s, off);
        s = __shfl(s, 0);
        float m = s * (1.0f / 64.0f);
        float d = v - m;
        float sq = d * d;
        for (int off = 32; off > 0; off >>= 1) sq += __shfl_down(sq, off);
        sq = __shfl(sq, 0);
        float var = sq * (1.0f / 64.0f);
        float inv = 1.0f / sqrtf(var + 1e-5f);
        xn[(size_t)row * MDD + lane] = f2bf(d * inv * g1[lane] + be1[lane]);
        return;
    }
    blk -= (BB * TT) / 4;
    if (blk < 128) {
        int id = blk * 256 + tid;
        int f = id >> 9;
        int wv = (id >> 3) & 63;
        int e = id & 7;
        int li = wv & 15, G = wv >> 4;
        float v;
        if (f < 24) {
            int mt = f >> 1, ks = f & 1;
            int n = mt * 16 + li;
            int k = ks * 32 + G * 8 + e;
            v = (n < 64) ? Wq[k * 64 + n] : (n < 128) ? Wk[k * 64 + (n - 64)] : Wv[k * 64 + (n - 128)];
        } else if (f < 32) {
            int g2i = f - 24;
            int mt = g2i >> 1, ks = g2i & 1;
            int n = mt * 16 + li;
            int k = ks * 32 + G * 8 + e;
            v = Wo[k * 64 + n];
        } else {
            int g2i = f - 32;
            int mt = g2i >> 1, ks = g2i & 1;
            int n = mt * 16 + li;
            int k = ks * 32 + G * 8 + e;
            v = Wn1[k * 256 + n];
        }
        Wall[id] = f2bf(v);
        return;
    }
    blk -= 128;
    {
        __shared__ float tile[32][33];
        int tk = blk & 31;
        int tn = blk >> 5;
        int c = tid & 31, r4 = tid >> 5;
        #pragma unroll
        for (int p = 0; p < 4; ++p) {
            int r = p * 8 + r4;
            tile[r][c] = W[(size_t)(tk * 32 + r) * GN + tn * 32 + c];
        }
        __syncthreads();
        #pragma unroll
        for (int p = 0; p < 4; ++p) {
            int r = p * 8 + r4;
            int n = tn * 32 + r;
            int kk = tk * 32 + c;
            int chunk = kk >> 6, slot = (kk >> 3) & 7, e = kk & 7;
            Wt[(size_t)n * GK + chunk * 64 + ((slot ^ (n & 7)) << 3) + e] = f2bf(tile[c][r]);
        }
    }
}

// ---------------- Kernel 4: fused block kernel, weights from L2, zero barriers ----------------
__global__ __launch_bounds__(256, 4) void k_main(const unsigned short* __restrict__ xnb,
                                              const int* __restrict__ idx,
                                              const float* __restrict__ bias,
                                              const unsigned short* __restrict__ Wall,
                                              const float* __restrict__ bq, const float* __restrict__ bk,
                                              const float* __restrict__ bv, const float* __restrict__ ls,
                                              const float* __restrict__ bo,
                                              const float* __restrict__ g2, const float* __restrict__ be2,
                                              const float* __restrict__ bn1, const float* __restrict__ Wn2,
                                              const float* __restrict__ bn2,
                                              const float* __restrict__ g3, const float* __restrict__ be3,
                                              unsigned short* __restrict__ xu) {
    __shared__ __align__(16) char L[TOKW * 8192];   // 32 KB
    const int tid = threadIdx.x;
    const int lane = tid & 63;
    const int li = lane & 15;
    const int G = lane >> 4;
    const int tok = tid >> 6;
    const int nglob = blockIdx.x * TOKW + tok;
    const int b = nglob >> 12;
    const int t = nglob & (TT - 1);
    const int asw = (li & 7) << 4;

    char* xgT = L + tok * 8192;
    char* qT  = xgT + 2048;
    char* kT  = xgT + 4096;
    char* vT  = xgT + 6144;                     // V^T: 64 c x 32B

    {
        int r16 = lane >> 2, part = lane & 3;
        int j = idx[t * NHH + r16];
        const uint4* sp = reinterpret_cast<const uint4*>(xnb + ((size_t)b * TT + j) * MDD + part * 16);
        uint4 w0 = sp[0], w1 = sp[1];
        int sw = (r16 & 7) << 4;
        *reinterpret_cast<uint4*>(xgT + r16 * 128 + ((part * 32) ^ sw)) = w0;
        *reinterpret_cast<uint4*>(xgT + r16 * 128 + ((part * 32 + 16) ^ sw)) = w1;
    }

    bf16x8 xf0 = *reinterpret_cast<const bf16x8*>(xgT + li * 128 + ((G * 16) ^ asw));
    bf16x8 xf1 = *reinterpret_cast<const bf16x8*>(xgT + li * 128 + ((64 + G * 16) ^ asw));
    f32x4 acc[12];
    #pragma unroll
    for (int mt = 0; mt < 12; ++mt) {
        bf16x8 w0 = *reinterpret_cast<const bf16x8*>(Wall + (mt * 2 + 0) * 512 + lane * 8);
        bf16x8 w1 = *reinterpret_cast<const bf16x8*>(Wall + (mt * 2 + 1) * 512 + lane * 8);
        f32x4 a = (f32x4){0.0f, 0.0f, 0.0f, 0.0f};
        a = __builtin_amdgcn_mfma_f32_16x16x32_bf16(w0, xf0, a, 0, 0, 0);
        a = __builtin_amdgcn_mfma_f32_16x16x32_bf16(w1, xf1, a, 0, 0, 0);
        acc[mt] = a;
    }

    float4 bias4[4];
    #pragma unroll
    for (int h = 0; h < 4; ++h)
        bias4[h] = *reinterpret_cast<const float4*>(bias + ((size_t)t * 4 + h) * 256 + li * 16 + G * 4);
    bf16x8 wo0[4], wo1[4];
    #pragma unroll
    for (int mt = 0; mt < 4; ++mt) {
        wo0[mt] = *reinterpret_cast<const bf16x8*>(Wall + (24 + mt * 2 + 0) * 512 + lane * 8);
        wo1[mt] = *reinterpret_cast<const bf16x8*>(Wall + (24 + mt * 2 + 1) * 512 + lane * 8);
    }
    float lsa[4] = {ls[0], ls[1], ls[2], ls[3]};

    #pragma unroll
    for (int h = 0; h < 4; ++h) {
        float4 b4 = *reinterpret_cast<const float4*>(bq + h * 16 + G * 4);
        float q0 = acc[h][0] + b4.x, q1 = acc[h][1] + b4.y, q2 = acc[h][2] + b4.z, q3 = acc[h][3] + b4.w;
        float sq = q0 * q0 + q1 * q1 + q2 * q2 + q3 * q3;
        sq += __shfl_xor(sq, 16); sq += __shfl_xor(sq, 32);
        float iq = 1.0f / fmaxf(sqrtf(sq), 1e-6f);
        uint2 u; u.x = pk2(q0 * iq, q1 * iq); u.y = pk2(q2 * iq, q3 * iq);
        *reinterpret_cast<uint2*>(qT + li * 128 + ((h * 32 + G * 8) ^ asw)) = u;
    }
    #pragma unroll
    for (int h = 0; h < 4; ++h) {
        float4 b4 = *reinterpret_cast<const float4*>(bk + h * 16 + G * 4);
        float k0 = acc[4 + h][0] + b4.x, k1 = acc[4 + h][1] + b4.y, k2 = acc[4 + h][2] + b4.z, k3 = acc[4 + h][3] + b4.w;
        float sk = k0 * k0 + k1 * k1 + k2 * k2 + k3 * k3;
        sk += __shfl_xor(sk, 16); sk += __shfl_xor(sk, 32);
        float ik = 1.0f / fmaxf(sqrtf(sk), 1e-6f);
        uint2 u; u.x = pk2(k0 * ik, k1 * ik); u.y = pk2(k2 * ik, k3 * ik);
        *reinterpret_cast<uint2*>(kT + li * 128 + ((h * 32 + G * 8) ^ asw)) = u;
    }
    #pragma unroll
    for (int m2 = 0; m2 < 4; ++m2) {
        float4 b4 = *reinterpret_cast<const float4*>(bv + m2 * 16 + G * 4);
        float v0 = acc[8 + m2][0] + b4.x, v1 = acc[8 + m2][1] + b4.y, v2 = acc[8 + m2][2] + b4.z, v3 = acc[8 + m2][3] + b4.w;
        int c0 = m2 * 16 + G * 4;
        *reinterpret_cast<unsigned short*>(vT + (c0 + 0) * 32 + li * 2) = f2bf(v0);
        *reinterpret_cast<unsigned short*>(vT + (c0 + 1) * 32 + li * 2) = f2bf(v1);
        *reinterpret_cast<unsigned short*>(vT + (c0 + 2) * 32 + li * 2) = f2bf(v2);
        *reinterpret_cast<unsigned short*>(vT + (c0 + 3) * 32 + li * 2) = f2bf(v3);
    }

    #pragma unroll
    for (int h = 0; h < 4; ++h) {
        bf16x8 kf8 = {}, qf8 = {};
        if (G < 2) {
            kf8 = *reinterpret_cast<const bf16x8*>(kT + li * 128 + ((h * 32 + G * 16) ^ asw));
            qf8 = *reinterpret_cast<const bf16x8*>(qT + li * 128 + ((h * 32 + G * 16) ^ asw));
        }
        f32x4 s4 = __builtin_amdgcn_mfma_f32_16x16x32_bf16(kf8, qf8, (f32x4){0.0f, 0.0f, 0.0f, 0.0f}, 0, 0, 0);
        float sch = __expf(fminf(lsa[h], 4.60517018598809136804f));
        float a0 = s4[0] * sch + bias4[h].x;
        float a1 = s4[1] * sch + bias4[h].y;
        float a2 = s4[2] * sch + bias4[h].z;
        float a3 = s4[3] * sch + bias4[h].w;
        float mx = fmaxf(fmaxf(a0, a1), fmaxf(a2, a3));
        mx = fmaxf(mx, __shfl_xor(mx, 16));
        mx = fmaxf(mx, __shfl_xor(mx, 32));
        float e0 = __expf(a0 - mx), e1 = __expf(a1 - mx), e2 = __expf(a2 - mx), e3 = __expf(a3 - mx);
        float sm = e0 + e1 + e2 + e3;
        sm += __shfl_xor(sm, 16);
        sm += __shfl_xor(sm, 32);
        float inv = 1.0f / sm;
        e0 *= inv; e1 *= inv; e2 *= inv; e3 *= inv;
        unsigned p01 = pk2(e0, e1), p23 = pk2(e2, e3);
        int s0l = li + 32 * (G & 1);
        uint4 pw;
        pw.x = (unsigned)__shfl((int)p01, s0l);
        pw.y = (unsigned)__shfl((int)p23, s0l);
        pw.z = (unsigned)__shfl((int)p01, s0l + 16);
        pw.w = (unsigned)__shfl((int)p23, s0l + 16);
        if (G >= 2) { pw.x = 0; pw.y = 0; pw.z = 0; pw.w = 0; }
        bf16x8 vf8 = {};
        if (G < 2) vf8 = *reinterpret_cast<const bf16x8*>(vT + (h * 16 + li) * 32 + G * 16);
        f32x4 pv = __builtin_amdgcn_mfma_f32_16x16x32_bf16(vf8, __builtin_bit_cast(bf16x8, pw),
                                                           (f32x4){0.0f, 0.0f, 0.0f, 0.0f}, 0, 0, 0);
        uint2 u; u.x = pk2(pv[0], pv[1]); u.y = pk2(pv[2], pv[3]);
        *reinterpret_cast<uint2*>(qT + li * 128 + ((h * 32 + G * 8) ^ asw)) = u;
    }

    float xfn[4][4];
    float rowadd;
    {
        bf16x8 av0 = *reinterpret_cast<const bf16x8*>(qT + li * 128 + ((G * 16) ^ asw));
        bf16x8 av1 = *reinterpret_cast<const bf16x8*>(qT + li * 128 + ((64 + G * 16) ^ asw));
        f32x4 oac[4];
        #pragma unroll
        for (int mt = 0; mt < 4; ++mt) {
            f32x4 a = (f32x4){0.0f, 0.0f, 0.0f, 0.0f};
            a = __builtin_amdgcn_mfma_f32_16x16x32_bf16(wo0[mt], av0, a, 0, 0, 0);
            a = __builtin_amdgcn_mfma_f32_16x16x32_bf16(wo1[mt], av1, a, 0, 0, 0);
            oac[mt] = a;
        }
        float xf[4][4];
        float s = 0.0f, sq = 0.0f;
        #pragma unroll
        for (int mt = 0; mt < 4; ++mt) {
            float4 bo4 = *reinterpret_cast<const float4*>(bo + mt * 16 + G * 4);
            uint2 xg2 = *reinterpret_cast<const uint2*>(xgT + li * 128 + ((mt * 32 + G * 8) ^ asw));
            float r0 = bf2f((unsigned short)(xg2.x & 0xffffu));
            float r1 = bf2f((unsigned short)(xg2.x >> 16));
            float r2 = bf2f((unsigned short)(xg2.y & 0xffffu));
            float r3 = bf2f((unsigned short)(xg2.y >> 16));
            xf[mt][0] = oac[mt][0] + bo4.x + r0;
            xf[mt][1] = oac[mt][1] + bo4.y + r1;
            xf[mt][2] = oac[mt][2] + bo4.z + r2;
            xf[mt][3] = oac[mt][3] + bo4.w + r3;
            #pragma unroll
            for (int r = 0; r < 4; ++r) { s += xf[mt][r]; sq += xf[mt][r] * xf[mt][r]; }
        }
        s += __shfl_xor(s, 16); s += __shfl_xor(s, 32);
        sq += __shfl_xor(sq, 16); sq += __shfl_xor(sq, 32);
        float m = s * (1.0f / 64.0f);
        float var = sq * (1.0f / 64.0f) - m * m;
        float inv = 1.0f / sqrtf(var + 1e-5f);
        #pragma unroll
        for (int mt = 0; mt < 4; ++mt) {
            float4 g24 = *reinterpret_cast<const float4*>(g2 + mt * 16 + G * 4);
            float4 be24 = *reinterpret_cast<const float4*>(be2 + mt * 16 + G * 4);
            xfn[mt][0] = (xf[mt][0] - m) * inv * g24.x + be24.x;
            xfn[mt][1] = (xf[mt][1] - m) * inv * g24.y + be24.y;
            xfn[mt][2] = (xf[mt][2] - m) * inv * g24.z + be24.z;
            xfn[mt][3] = (xf[mt][3] - m) * inv * g24.w + be24.w;
            uint2 u; u.x = pk2(xfn[mt][0], xfn[mt][1]); u.y = pk2(xfn[mt][2], xfn[mt][3]);
            *reinterpret_cast<uint2*>(kT + li * 128 + ((mt * 32 + G * 8) ^ asw)) = u;
        }
    }

    {
        bf16x8 xn0 = *reinterpret_cast<const bf16x8*>(kT + li * 128 + ((G * 16) ^ asw));
        bf16x8 xn1 = *reinterpret_cast<const bf16x8*>(kT + li * 128 + ((64 + G * 16) ^ asw));
        float dot = 0.0f;
        #pragma unroll
        for (int mt = 0; mt < 16; ++mt) {
            bf16x8 w0 = *reinterpret_cast<const bf16x8*>(Wall + (32 + mt * 2 + 0) * 512 + lane * 8);
            bf16x8 w1 = *reinterpret_cast<const bf16x8*>(Wall + (32 + mt * 2 + 1) * 512 + lane * 8);
            f32x4 a = (f32x4){0.0f, 0.0f, 0.0f, 0.0f};
            a = __builtin_amdgcn_mfma_f32_16x16x32_bf16(w0, xn0, a, 0, 0, 0);
            a = __builtin_amdgcn_mfma_f32_16x16x32_bf16(w1, xn1, a, 0, 0, 0);
            float4 bn14 = *reinterpret_cast<const float4*>(bn1 + mt * 16 + G * 4);
            float4 w24 = *reinterpret_cast<const float4*>(Wn2 + mt * 16 + G * 4);
            dot += lrelu(a[0] + bn14.x) * w24.x;
            dot += lrelu(a[1] + bn14.y) * w24.y;
            dot += lrelu(a[2] + bn14.z) * w24.z;
            dot += lrelu(a[3] + bn14.w) * w24.w;
        }
        dot += __shfl_xor(dot, 16);
        dot += __shfl_xor(dot, 32);
        rowadd = lrelu(dot + bn2[0]);
    }

    {
        float s = 0.0f, sq = 0.0f;
        float vals[4][4];
        #pragma unroll
        for (int mt = 0; mt < 4; ++mt)
            #pragma unroll
            for (int r = 0; r < 4; ++r) {
                float v = xfn[mt][r] + rowadd;
                vals[mt][r] = v;
                s += v; sq += v * v;
            }
        s += __shfl_xor(s, 1); s += __shfl_xor(s, 2); s += __shfl_xor(s, 4);
        s += __shfl_xor(s, 8); s += __shfl_xor(s, 16); s += __shfl_xor(s, 32);
        sq += __shfl_xor(sq, 1); sq += __shfl_xor(sq, 2); sq += __shfl_xor(sq, 4);
        sq += __shfl_xor(sq, 8); sq += __shfl_xor(sq, 16); sq += __shfl_xor(sq, 32);
        float m = s * (1.0f / 1024.0f);
        float var = sq * (1.0f / 1024.0f) - m * m;
        float inv = 1.0f / sqrtf(var + 1e-5f);
        int swm = nglob & 7;
        #pragma unroll
        for (int mt = 0; mt < 4; ++mt) {
            int o0 = li * 64 + mt * 16 + G * 4;
            float4 g34 = *reinterpret_cast<const float4*>(g3 + o0);
            float4 be34 = *reinterpret_cast<const float4*>(be3 + o0);
            float u0 = (vals[mt][0] - m) * inv * g34.x + be34.x;
            float u1 = (vals[mt][1] - m) * inv * g34.y + be34.y;
            float u2 = (vals[mt][2] - m) * inv * g34.z + be34.z;
            float u3 = (vals[mt][3] - m) * inv * g34.w + be34.w;
            uint2 u; u.x = pk2(u0, u1); u.y = pk2(u2, u3);
            size_t p = (size_t)nglob * 1024 + li * 64
                     + ((((mt * 2 + (G >> 1)) ^ swm) << 3) | ((G & 1) * 4));
            *reinterpret_cast<uint2*>(xu + p) = u;
        }
    }
}

// ---------------- Kernel 5b: MFMA GEMM, counted-vmcnt pipeline + XCD-aware tile swizzle (T1) ----
__global__ __launch_bounds__(256) void k_gemm(const unsigned short* __restrict__ xu,
                                              const unsigned short* __restrict__ Wt,
                                              const float* __restrict__ bu1,
                                              const float* __restrict__ Wu2,
                                              float* __restrict__ partial) {
    // XCD-aware remap: hardware round-robins linear id across 8 XCDs (id & 7).
    // Give XCD x a contiguous bm range [x*32, x*32+32), iterating all 8 bn per bm
    // consecutively -> A-panel (256 KB) and all B-panels (2 MB) stay L2-resident.
    int id = blockIdx.x;                       // 0..2047
    int xcd = id & 7;
    int slot = id >> 3;                        // 0..255
    int bm = xcd * 32 + (slot >> 3);           // 0..255
    int bn = slot & 7;                         // 0..7
    int tid = threadIdx.x;
    int w = tid >> 6, l = tid & 63;
    int wm = w >> 1, wn = w & 1;
    int lr = l & 15, lg = l >> 4;

    __shared__ __align__(1024) unsigned short LB[4 * BMt * BKt];   // 64 KB
    __shared__ float rowpart[2][BMt];
    char* base = reinterpret_cast<char*>(LB);

    f32x4 acc[4][4];
    #pragma unroll
    for (int i = 0; i < 4; ++i)
        #pragma unroll
        for (int j = 0; j < 4; ++j)
            acc[i][j] = (f32x4){0.0f, 0.0f, 0.0f, 0.0f};

    const size_t arow = (size_t)(bm * BMt) * GK;
    const size_t brow = (size_t)(bn * BNt) * GK;

    #define STAGE(kt, buf)                                                            \
        {                                                                             \
            char* Ab_ = base + (buf) * 32768;                                         \
            char* Bb_ = Ab_ + 16384;                                                  \
            int k0_ = (kt) * BKt;                                                     \
            _Pragma("unroll")                                                         \
            for (int p = 0; p < 4; ++p) {                                             \
                int seg = w * 4 + p;                                                  \
                int rl = seg * 8 + (l >> 3);                                          \
                gload16(xu + arow + (size_t)rl * GK + k0_ + (l & 7) * 8, Ab_ + seg * 1024); \
                gload16(Wt + brow + (size_t)rl * GK + k0_ + (l & 7) * 8, Bb_ + seg * 1024); \
            }                                                                         \
        }

    STAGE(0, 0)

    for (int kt = 0; kt < GK / BKt; ++kt) {
        int buf = kt & 1;
        if (kt < GK / BKt - 1) {
            STAGE(kt + 1, buf ^ 1)
            asm volatile("s_waitcnt vmcnt(8)" ::: "memory");
        } else {
            asm volatile("s_waitcnt vmcnt(0)" ::: "memory");
        }
        __builtin_amdgcn_sched_barrier(0);
        __builtin_amdgcn_s_barrier();
        __builtin_amdgcn_sched_barrier(0);
        char* Ab = base + buf * 32768;
        char* Bb = Ab + 16384;
        #pragma unroll
        for (int ks = 0; ks < 2; ++ks) {
            bf16x8 af[4], bfr[4];
            #pragma unroll
            for (int rf = 0; rf < 4; ++rf) {
                int row = wm * 64 + rf * 16 + lr;
                int coff = (ks * 64 + lg * 16) ^ ((row & 7) << 4);
                af[rf] = *reinterpret_cast<const bf16x8*>(Ab + row * 128 + coff);
            }
            #pragma unroll
            for (int nf = 0; nf < 4; ++nf) {
                int rowb = wn * 64 + nf * 16 + lr;
                int coff = (ks * 64 + lg * 16) ^ ((rowb & 7) << 4);
                bfr[nf] = *reinterpret_cast<const bf16x8*>(Bb + rowb * 128 + coff);
            }
            #pragma unroll
            for (int rf = 0; rf < 4; ++rf)
                #pragma unroll
                for (int nf = 0; nf < 4; ++nf)
                    acc[rf][nf] = __builtin_amdgcn_mfma_f32_16x16x32_bf16(af[rf], bfr[nf], acc[rf][nf], 0, 0, 0);
        }
        __builtin_amdgcn_sched_barrier(0);
        __builtin_amdgcn_s_barrier();
    }
    #undef STAGE

    float b1v[4], w2v[4];
    #pragma unroll
    for (int nf = 0; nf < 4; ++nf) {
        int nn = bn * BNt + wn * 64 + nf * 16 + lr;
        b1v[nf] = bu1[nn];
        w2v[nf] = Wu2[nn];
    }
    float rowsum[4][4];
    #pragma unroll
    for (int rf = 0; rf < 4; ++rf) {
        #pragma unroll
        for (int j = 0; j < 4; ++j) {
            float s = 0.0f;
            #pragma unroll
            for (int nf = 0; nf < 4; ++nf)
                s += lrelu(acc[rf][nf][j] + b1v[nf]) * w2v[nf];
            #pragma unroll
            for (int off = 1; off < 16; off <<= 1)
                s += __shfl_xor(s, off);
            rowsum[rf][j] = s;
        }
    }
    if (lr == 0) {
        #pragma unroll
        for (int rf = 0; rf < 4; ++rf)
            #pragma unroll
            for (int j = 0; j < 4; ++j)
                rowpart[wn][wm * 64 + rf * 16 + lg * 4 + j] = rowsum[rf][j];
    }
    __syncthreads();
    if (tid < BMt) {
        float v = rowpart[0][tid] + rowpart[1][tid];
        partial[((size_t)(bm * BMt + tid)) * NCHUNK + bn] = v;
    }
}

// ---------------- Kernel 5c: sum partials + bias + lrelu ----------------
__global__ __launch_bounds__(256) void k_reduce(const float* __restrict__ partial,
                                                const float* __restrict__ bu2,
                                                float* __restrict__ out) {
    int m = blockIdx.x * 256 + threadIdx.x;
    float s = bu2[0];
    #pragma unroll
    for (int c = 0; c < NCHUNK; ++c) s += partial[(size_t)m * NCHUNK + c];
    out[m] = lrelu(s);
}

extern "C" void kernel_launch(void* const* d_in, const int* in_sizes, int n_in,
                              void* d_out, int out_size, void* d_ws, size_t ws_size,
                              hipStream_t stream) {
    const float* x   = (const float*)d_in[0];
    const float* c1  = (const float*)d_in[1];
    const float* c2  = (const float*)d_in[2];
    const float* g1  = (const float*)d_in[3];
    const float* be1 = (const float*)d_in[4];
    const float* Wq  = (const float*)d_in[5];
    const float* bq  = (const float*)d_in[6];
    const float* Wk  = (const float*)d_in[7];
    const float* bk  = (const float*)d_in[8];
    const float* Wv  = (const float*)d_in[9];
    const float* bv  = (const float*)d_in[10];
    const float* ls  = (const float*)d_in[11];
    const float* Wo  = (const float*)d_in[12];
    const float* bo  = (const float*)d_in[13];
    const float* Wp1 = (const float*)d_in[14];
    const float* bp1 = (const float*)d_in[15];
    const float* Wp2 = (const float*)d_in[16];
    const float* bp2 = (const float*)d_in[17];
    const float* g2  = (const float*)d_in[18];
    const float* be2 = (const float*)d_in[19];
    const float* Wn1 = (const float*)d_in[20];
    const float* bn1 = (const float*)d_in[21];
    const float* Wn2 = (const float*)d_in[22];
    const float* bn2 = (const float*)d_in[23];
    const float* g3  = (const float*)d_in[24];
    const float* be3 = (const float*)d_in[25];
    const float* Wu1 = (const float*)d_in[26];
    const float* bu1 = (const float*)d_in[27];
    const float* Wu2 = (const float*)d_in[28];
    const float* bu2 = (const float*)d_in[29];
    float* out = (float*)d_out;

    char* ws = (char*)d_ws;
    size_t off = 0;
    int*   idx  = (int*)(ws + off);   off += (size_t)TT * NHH * 4;
    float* c1n  = (float*)(ws + off); off += (size_t)TT * NHH * 4;
    float* c2n  = (float*)(ws + off); off += (size_t)TT * NHH * 4;
    float* bias = (float*)(ws + off); off += (size_t)TT * HEADSS * NHH * NHH * 4;   // 16 MB
    unsigned short* xnb  = (unsigned short*)(ws + off); off += (size_t)BB * TT * MDD * 2;   // 4 MB
    unsigned short* xuB  = (unsigned short*)(ws + off); off += (size_t)GM * GK * 2;         // 64 MB
    unsigned short* Wu1t = (unsigned short*)(ws + off); off += (size_t)GK * GN * 2;         // 2 MB
    float* partial = (float*)(ws + off); off += (size_t)GM * NCHUNK * 4;                    // 1 MB
    unsigned short* Wall = (unsigned short*)(ws + off); off += 64 * 1024;                   // 64 KB

    k_front<<<TT + (BB * TT) / 4 + 128 + 1024, 256, 0, stream>>>(
        c1, c2, Wp1, bp1, Wp2, bp2, idx, c1n, c2n, bias,
        x, g1, be1, xnb, Wq, Wk, Wv, Wo, Wn1, Wall, Wu1, Wu1t);
    k_main<<<(BB * TT) / TOKW, 256, 0, stream>>>(xnb, idx, bias, Wall,
                                                 bq, bk, bv, ls, bo, g2, be2, bn1, Wn2, bn2, g3, be3, xuB);
    k_gemm<<<(GM / BMt) * (GN / BNt), 256, 0, stream>>>(xuB, Wu1t, bu1, Wu2, partial);
    k_reduce<<<GM / 256, 256, 0, stream>>>(partial, bu2, out);
}